// Round 1
// baseline (2428.711 us; speedup 1.0000x reference)
//
#include <hip/hip_runtime.h>
#include <hip/hip_bf16.h>
#include <math.h>

typedef __bf16 bf16_t;
typedef __bf16 bf16x8 __attribute__((ext_vector_type(8)));
typedef float  f32x4  __attribute__((ext_vector_type(4)));

#define EPSF 1e-5f
#define TAUF 1.5f

__device__ __forceinline__ float sigmoidf_(float x){ return 1.f/(1.f+__expf(-x)); }
__device__ __forceinline__ float siluf_(float x){ return x*sigmoidf_(x); }

// ---------------- p[b,c] = mean_hw(x) ----------------
__global__ void k_pool(const float* __restrict__ x, float* __restrict__ p){
  int bc = blockIdx.x; const float* xr = x + (size_t)bc*4096;
  float s = 0.f;
  for (int i = threadIdx.x; i < 4096; i += 256) s += xr[i];
  __shared__ float sb[4];
  for (int off=32; off; off>>=1) s += __shfl_down(s, off);
  if ((threadIdx.x & 63)==0) sb[threadIdx.x>>6] = s;
  __syncthreads();
  if (threadIdx.x==0) p[bc] = (sb[0]+sb[1]+sb[2]+sb[3]) * (1.f/4096.f);
}

// ---------------- per-b tiny MLPs: g (global-context gate), gate = g*c_attn ----------------
__global__ void k_small1(const float* __restrict__ p, const float* __restrict__ gc_w1,
                         const float* __restrict__ gc_w2, const float* __restrict__ cg_w1,
                         const float* __restrict__ cg_b1, const float* __restrict__ cg_w2,
                         const float* __restrict__ cg_b2,
                         float* __restrict__ gbuf, float* __restrict__ gate){
  int b = blockIdx.x; int t = threadIdx.x; // 128 threads
  __shared__ float ps[128], h1[32], pc[128], c1[16];
  ps[t] = p[b*128+t];
  __syncthreads();
  if (t < 32){ float a=0.f; for(int c=0;c<128;c++) a += ps[c]*gc_w1[t*128+c]; h1[t]=siluf_(a); }
  __syncthreads();
  float a=0.f; for(int j=0;j<32;j++) a += h1[j]*gc_w2[t*32+j];
  float g = sigmoidf_(a);
  gbuf[b*128+t] = g; pc[t] = ps[t]*g;   // mean(x*g) = g*mean(x)
  __syncthreads();
  if (t < 16){ float a2=cg_b1[t]; for(int c=0;c<128;c++) a2 += pc[c]*cg_w1[t*128+c]; c1[t]=siluf_(a2); }
  __syncthreads();
  float a3=cg_b2[t]; for(int j=0;j<16;j++) a3 += c1[j]*cg_w2[t*16+j];
  gate[b*128+t] = g * sigmoidf_(a3);
}

// ---------------- s_in: mean/max over channels of x*g ----------------
__global__ void k_spatial(const float* __restrict__ x, const float* __restrict__ gbuf,
                          float* __restrict__ sin_){
  int bi = blockIdx.x; int b = bi>>4; int h = ((bi&15)<<2) + (threadIdx.x>>6); int w = threadIdx.x&63;
  float sm=0.f, mx=-1e30f;
  for (int c=0;c<128;c++){
    float v = x[(((size_t)(b*128+c))*64 + h)*64 + w] * gbuf[b*128+c];
    sm += v; mx = fmaxf(mx, v);
  }
  sin_[b*8192 + h*64 + w]        = sm*(1.f/128.f);
  sin_[b*8192 + 4096 + h*64 + w] = mx;
}

// ---------------- 7x7 spatial-gate conv ----------------
__global__ void k_sgconv(const float* __restrict__ sin_, const float* __restrict__ sg_w,
                         float* __restrict__ satt){
  int bi = blockIdx.x; int b = bi>>4; int h = ((bi&15)<<2)+(threadIdx.x>>6); int w = threadIdx.x&63;
  float a = 0.f;
  for (int c2=0;c2<2;c2++){
    const float* sp = sin_ + b*8192 + c2*4096;
    const float* wp = sg_w + c2*49;
    for (int di=0;di<7;di++){ int hh=h+di-3; if (hh<0||hh>=64) continue;
      for (int dj=0;dj<7;dj++){ int ww=w+dj-3; if (ww<0||ww>=64) continue;
        a += sp[hh*64+ww]*wp[di*7+dj]; } }
  }
  satt[b*4096 + h*64 + w] = sigmoidf_(a);
}

// ---------------- x2 = x*g*c_attn*s_attn -> channels-last padded bf16; pooled sum via atomics ----------------
__global__ void k_x2(const float* __restrict__ x, const float* __restrict__ gate,
                     const float* __restrict__ satt, bf16_t* __restrict__ x2t,
                     float* __restrict__ pc2){
  int bi = blockIdx.x; int b = bi>>6; int h = bi&63;
  __shared__ bf16_t tile[128*66];
  int wv = threadIdx.x>>6, lane = threadIdx.x&63;
  float sa = satt[b*4096 + h*64 + lane];
  for (int it=0; it<32; it++){
    int c = it*4 + wv;
    float v = x[(((size_t)(b*128+c))*64 + h)*64 + lane] * gate[b*128+c] * sa;
    tile[c*66 + lane] = (bf16_t)v;
    float s = v;
    for (int off=32; off; off>>=1) s += __shfl_down(s, off);
    if (lane==0) atomicAdd(&pc2[b*128+c], s);
  }
  __syncthreads();
  for (int it=0; it<32; it++){
    int w = it*2 + (threadIdx.x>>7); int c = threadIdx.x&127;
    x2t[(((size_t)(b*66) + (h+1))*66 + (w+1))*128 + c] = tile[c*66 + w];
  }
}

// ---------------- gf = silu(mean(x2) @ rg_w^T) ----------------
__global__ void k_small2(const float* __restrict__ pc2, const float* __restrict__ rg_w,
                         float* __restrict__ gf){
  int b = blockIdx.x; int t = threadIdx.x;
  if (t < 32){
    float a=0.f; for(int c=0;c<128;c++) a += pc2[b*128+c]*(1.f/4096.f)*rg_w[t*128+c];
    gf[b*32+t] = siluf_(a);
  }
}

// ---------------- weight prep: WC[(s*128+o)][t*128+c] bf16, RCW2[t][c][hid] f32 ----------------
__global__ void k_wprep(const float* __restrict__ base_w, const float* __restrict__ delta_w,
                        const float* __restrict__ kscale, const float* __restrict__ rc_w,
                        bf16_t* __restrict__ WC, float* __restrict__ RCW2){
  int i = blockIdx.x*256 + threadIdx.x;
  if (i < 640*1152){
    int r = i/1152; int kk = i - r*1152; int t = kk>>7; int c = kk&127;
    int s = r>>7; int o = r&127;
    float v;
    if (s==0) v = base_w[(o*128+c)*9 + t];
    else { int k = s-1; v = delta_w[(((k*128)+o)*128 + c)*9 + t] * kscale[k*128+o]; }
    WC[i] = (bf16_t)v;
  } else {
    int i2 = i - 640*1152;
    if (i2 < 9*128*32){
      int t = i2>>12; int c = (i2>>5)&127; int hid = i2&31;
      RCW2[i2] = rc_w[(hid*128+c)*9 + t];
    }
  }
}

// ---------------- router: lf = silu(BN(dilated conv(x2))) + gf, channels-last ----------------
__global__ void __launch_bounds__(256) k_router(
    const bf16_t* __restrict__ x2t, const float* __restrict__ RCW2,
    const float* __restrict__ bn_gamma, const float* __restrict__ bn_beta,
    const float* __restrict__ bn_mean, const float* __restrict__ bn_var,
    const float* __restrict__ gf, float* __restrict__ lf){
  int bi = blockIdx.x; int b = bi>>6; int h = bi&63;
  int w = threadIdx.x&63; int hg = threadIdx.x>>6;
  float acc[8]; for(int j=0;j<8;j++) acc[j]=0.f;
  for (int t=0;t<9;t++){
    int di=t/3, dj=t-di*3;
    int hs = h + 2*di - 1; if (hs<0||hs>65) continue;
    int ws = w + 2*dj - 1; if (ws<0||ws>65) continue;
    const bf16_t* xp = x2t + (((size_t)(b*66)+hs)*66 + ws)*128;
    const float*  wp = RCW2 + t*4096 + hg*8;
    for (int c8=0;c8<16;c8++){
      bf16x8 xv = *(const bf16x8*)(xp + c8*8);
      #pragma unroll
      for (int e=0;e<8;e++){
        float xf = (float)xv[e];
        const float* wr = wp + (c8*8+e)*32;
        float4 w0 = *(const float4*)(wr);
        float4 w1 = *(const float4*)(wr+4);
        acc[0]+=xf*w0.x; acc[1]+=xf*w0.y; acc[2]+=xf*w0.z; acc[3]+=xf*w0.w;
        acc[4]+=xf*w1.x; acc[5]+=xf*w1.y; acc[6]+=xf*w1.z; acc[7]+=xf*w1.w;
      }
    }
  }
  int pos = b*4096 + h*64 + w;
  #pragma unroll
  for (int j=0;j<8;j++){
    int hid = hg*8 + j;
    float aa = bn_gamma[hid]*rsqrtf(bn_var[hid]+EPSF);
    float bb = bn_beta[hid] - bn_mean[hid]*aa;
    lf[(size_t)pos*32 + hid] = siluf_(aa*acc[j]+bb) + gf[b*32+hid];
  }
}

// ---------------- main dynamic conv: implicit-GEMM MFMA + fused gate/softmax/combine ----------------
__global__ void __launch_bounds__(256) k_main(
    const bf16_t* __restrict__ x2t, const bf16_t* __restrict__ WC,
    const float* __restrict__ lf, const float* __restrict__ gate_w,
    const float* __restrict__ gate_b, float* __restrict__ outp){
  __shared__ __align__(16) char smem[33792];
  bf16_t* Ash = (bf16_t*)smem;              // 128 x 40 (10240 B)
  bf16_t* Bsh = (bf16_t*)(smem + 10240);    // 160 x 40 (12800 B)
  float*  shLF = (float*)smem;              // epilogue reuse: 128 x 33
  float*  shGW = (float*)(smem + 16896);    // 128 x 33

  int tid = threadIdx.x;
  int wv = tid>>6, lane = tid&63, m16 = lane&15, q = lane>>4;
  int bx = blockIdx.x;
  int ot = bx & 3; int bh2 = bx >> 2; int b = bh2 >> 5; int h0 = (bh2 & 31) << 1;
  int obase = ot*32;

  f32x4 acc[2][5][2] = {};

  const bf16_t* xb = x2t + (size_t)b*66*66*128;

  for (int t=0;t<9;t++){
    int di = t/3, dj = t - di*3;
    for (int cb=0; cb<4; cb++){
      // stage A: 128 rows (2 image rows x 64 w) x 32 k (channels)
      #pragma unroll
      for (int it=0; it<2; it++){
        int idx = tid + it*256;
        int m = idx>>2, seg = idx&3;
        int hm = h0 + (m>>6), wm = m&63;
        const bf16_t* src = xb + (((size_t)(hm+di)*66) + (wm+dj))*128 + cb*32 + seg*8;
        *(uint4*)(Ash + m*40 + seg*8) = *(const uint4*)src;
      }
      // stage B: 160 rows (5 segs x 32 o) x 32 k
      for (int idx = tid; idx < 640; idx += 256){
        int r = idx>>2, seg = idx&3;
        int s = r>>5, o2 = r&31;
        const bf16_t* src = WC + ((size_t)(s*128 + obase + o2))*1152 + t*128 + cb*32 + seg*8;
        *(uint4*)(Bsh + r*40 + seg*8) = *(const uint4*)src;
      }
      __syncthreads();
      bf16x8 av0 = *(const bf16x8*)(Ash + ((wv*2+0)*16 + m16)*40 + q*8);
      bf16x8 av1 = *(const bf16x8*)(Ash + ((wv*2+1)*16 + m16)*40 + q*8);
      #pragma unroll
      for (int s=0;s<5;s++){
        #pragma unroll
        for (int u=0;u<2;u++){
          bf16x8 bv = *(const bf16x8*)(Bsh + ((s*32 + u*16) + m16)*40 + q*8);
          acc[0][s][u] = __builtin_amdgcn_mfma_f32_16x16x32_bf16(av0, bv, acc[0][s][u], 0,0,0);
          acc[1][s][u] = __builtin_amdgcn_mfma_f32_16x16x32_bf16(av1, bv, acc[1][s][u], 0,0,0);
        }
      }
      __syncthreads();
    }
  }

  // epilogue: fused gate einsum + softmax(K) + base/delta combine
  for (int idx = tid; idx < 4096; idx += 256){
    int m = idx>>5, j = idx&31;
    shLF[m*33+j] = lf[((size_t)b*4096 + h0*64)*32 + idx];
  }
  for (int idx = tid; idx < 4096; idx += 256){
    int r = idx>>5, j = idx&31;
    int k = r>>5, o2 = r&31;
    shGW[r*33+j] = gate_w[(k*128 + obase + o2)*32 + j];
  }
  __syncthreads();
  #pragma unroll
  for (int mi=0; mi<2; mi++){
    #pragma unroll
    for (int i=0;i<4;i++){
      int ml = (wv*2+mi)*16 + q*4 + i;
      const float* lfr = shLF + ml*33;
      int l = h0*64 + ml;
      #pragma unroll
      for (int u=0;u<2;u++){
        int o2 = u*16 + m16;
        float lg[4];
        #pragma unroll
        for (int k=0;k<4;k++){
          float a = gate_b[k*128 + obase + o2];
          const float* wr = shGW + (k*32+o2)*33;
          #pragma unroll
          for (int j=0;j<32;j++) a += lfr[j]*wr[j];
          lg[k] = a * (1.f/TAUF);
        }
        float mx = fmaxf(fmaxf(lg[0],lg[1]),fmaxf(lg[2],lg[3]));
        float e0=__expf(lg[0]-mx), e1=__expf(lg[1]-mx), e2=__expf(lg[2]-mx), e3=__expf(lg[3]-mx);
        float inv = 1.f/(e0+e1+e2+e3);
        float y = acc[mi][0][u][i] +
                  (e0*acc[mi][1][u][i] + e1*acc[mi][2][u][i] +
                   e2*acc[mi][3][u][i] + e3*acc[mi][4][u][i])*inv;
        outp[((size_t)(b*128 + obase + o2))*4096 + l] = y;
      }
    }
  }
}

// ---------------- per-(b,o) sum & sumsq ----------------
__global__ void k_chanred(const float* __restrict__ outp, float* __restrict__ csum, float* __restrict__ cssq){
  int bo = blockIdx.x; const float* r = outp + (size_t)bo*4096;
  float s=0.f, s2=0.f;
  for (int i=threadIdx.x;i<4096;i+=256){ float v=r[i]; s+=v; s2+=v*v; }
  __shared__ float b1[4], b2[4];
  for (int off=32; off; off>>=1){ s += __shfl_down(s,off); s2 += __shfl_down(s2,off); }
  if ((threadIdx.x&63)==0){ b1[threadIdx.x>>6]=s; b2[threadIdx.x>>6]=s2; }
  __syncthreads();
  if (threadIdx.x==0){ csum[bo]=b1[0]+b1[1]+b1[2]+b1[3]; cssq[bo]=b2[0]+b2[1]+b2[2]+b2[3]; }
}

// ---------------- GroupNorm stats + output-SE -> per-(b,o) affine ----------------
__global__ void k_small3(const float* __restrict__ csum, const float* __restrict__ cssq,
                         const float* __restrict__ gn_gamma, const float* __restrict__ gn_beta,
                         const float* __restrict__ se_w1, const float* __restrict__ se_b1,
                         const float* __restrict__ se_w2, const float* __restrict__ se_b2,
                         float* __restrict__ sca, float* __restrict__ shb){
  int b = blockIdx.x; int o = threadIdx.x; // 128
  __shared__ float s1[128], s2[128], gmu[8], grs[8], psl[128], t1[16];
  s1[o] = csum[b*128+o]; s2[o] = cssq[b*128+o];
  __syncthreads();
  if (o<8){
    float a=0.f,a2=0.f; for(int j=0;j<16;j++){ a+=s1[o*16+j]; a2+=s2[o*16+j]; }
    float mu = a*(1.f/65536.f); float var = a2*(1.f/65536.f) - mu*mu;
    gmu[o]=mu; grs[o]=rsqrtf(var+EPSF);
  }
  __syncthreads();
  int g = o>>4;
  psl[o] = (s1[o]*(1.f/4096.f) - gmu[g])*grs[g]*gn_gamma[o] + gn_beta[o];
  __syncthreads();
  if (o<16){ float a = se_b1[o]; for(int c=0;c<128;c++) a += psl[c]*se_w1[o*128+c]; t1[o]=siluf_(a); }
  __syncthreads();
  float a = se_b2[o]; for(int j=0;j<16;j++) a += t1[j]*se_w2[o*16+j];
  float sev = sigmoidf_(a);
  sca[b*128+o] = grs[g]*gn_gamma[o]*sev;
  shb[b*128+o] = (gn_beta[o] - gmu[g]*grs[g]*gn_gamma[o])*sev;
}

// ---------------- final: GN-affine*SE + tanh(identity_scale)*x + bias ----------------
__global__ void k_final(const float* __restrict__ outp, const float* __restrict__ x,
                        const float* __restrict__ sca, const float* __restrict__ shb,
                        const float* __restrict__ bias, const float* __restrict__ iscale,
                        float* __restrict__ out){
  float ts = tanhf(iscale[0]);
  int i4 = blockIdx.x*256 + threadIdx.x;
  #pragma unroll
  for (int rep=0; rep<2; rep++){
    size_t i = (size_t)i4*4;
    int bo = (int)(i>>12); int o = bo&127;
    float4 xo = *(const float4*)(outp+i);
    float4 xi = *(const float4*)(x+i);
    float A = sca[bo], Bv = shb[bo], bz = bias[o];
    float4 r;
    r.x = xo.x*A + Bv + ts*xi.x + bz;
    r.y = xo.y*A + Bv + ts*xi.y + bz;
    r.z = xo.z*A + Bv + ts*xi.z + bz;
    r.w = xo.w*A + Bv + ts*xi.w + bz;
    *(float4*)(out+i) = r;
    i4 += 4096*256;
  }
}

extern "C" void kernel_launch(void* const* d_in, const int* in_sizes, int n_in,
                              void* d_out, int out_size, void* d_ws, size_t ws_size,
                              hipStream_t stream){
  const float* x      = (const float*)d_in[0];
  const float* base_w = (const float*)d_in[1];
  const float* delta_w= (const float*)d_in[2];
  const float* kscale = (const float*)d_in[3];
  const float* gc_w1  = (const float*)d_in[4];
  const float* gc_w2  = (const float*)d_in[5];
  const float* rc_w   = (const float*)d_in[6];
  const float* bn_g   = (const float*)d_in[7];
  const float* bn_b   = (const float*)d_in[8];
  const float* bn_m   = (const float*)d_in[9];
  const float* bn_v   = (const float*)d_in[10];
  const float* rg_w   = (const float*)d_in[11];
  const float* gate_w = (const float*)d_in[12];
  const float* gate_b = (const float*)d_in[13];
  const float* cg_w1  = (const float*)d_in[14];
  const float* cg_b1  = (const float*)d_in[15];
  const float* cg_w2  = (const float*)d_in[16];
  const float* cg_b2  = (const float*)d_in[17];
  const float* sg_w   = (const float*)d_in[18];
  const float* gn_g   = (const float*)d_in[19];
  const float* gn_b   = (const float*)d_in[20];
  const float* se_w1  = (const float*)d_in[21];
  const float* se_b1  = (const float*)d_in[22];
  const float* se_w2  = (const float*)d_in[23];
  const float* se_b2  = (const float*)d_in[24];
  const float* iscale = (const float*)d_in[25];
  const float* bias   = (const float*)d_in[26];
  float* out = (float*)d_out;

  char* ws = (char*)d_ws;
  size_t off = 0;
  auto alloc = [&](size_t bytes)->void*{ void* p = ws + off; off += (bytes + 255) & ~(size_t)255; return p; };
  bf16_t* X2T = (bf16_t*)alloc(16ull*66*66*128*2);   // padded channels-last gated input
  bf16_t* WC  = (bf16_t*)alloc(640ull*1152*2);       // combined base+delta weights
  float* RCW2 = (float*)alloc(9ull*128*32*4);        // router weights [t][c][hid]
  float* LF   = (float*)alloc(16ull*4096*32*4);      // router features channels-last
  float* OUTP = (float*)alloc(16ull*128*4096*4);     // pre-GN output
  float* P    = (float*)alloc(2048*4);
  float* GB   = (float*)alloc(2048*4);
  float* GATE = (float*)alloc(2048*4);
  float* PC2  = (float*)alloc(2048*4);
  float* GF   = (float*)alloc(512*4);
  float* SIN  = (float*)alloc(16ull*8192*4);
  float* SATT = (float*)alloc(16ull*4096*4);
  float* CSUM = (float*)alloc(2048*4);
  float* CSSQ = (float*)alloc(2048*4);
  float* SCA  = (float*)alloc(2048*4);
  float* SHB  = (float*)alloc(2048*4);

  hipMemsetAsync(X2T, 0, 16ull*66*66*128*2, stream); // zero pad borders
  hipMemsetAsync(PC2, 0, 2048*4, stream);

  k_wprep  <<<3024, 256, 0, stream>>>(base_w, delta_w, kscale, rc_w, WC, RCW2);
  k_pool   <<<2048, 256, 0, stream>>>(x, P);
  k_small1 <<<16,   128, 0, stream>>>(P, gc_w1, gc_w2, cg_w1, cg_b1, cg_w2, cg_b2, GB, GATE);
  k_spatial<<<256,  256, 0, stream>>>(x, GB, SIN);
  k_sgconv <<<256,  256, 0, stream>>>(SIN, sg_w, SATT);
  k_x2     <<<1024, 256, 0, stream>>>(x, GATE, SATT, X2T, PC2);
  k_small2 <<<16,    64, 0, stream>>>(PC2, rg_w, GF);
  k_router <<<1024, 256, 0, stream>>>(X2T, RCW2, bn_g, bn_b, bn_m, bn_v, GF, LF);
  k_main   <<<2048, 256, 0, stream>>>(X2T, WC, LF, gate_w, gate_b, OUTP);
  k_chanred<<<2048, 256, 0, stream>>>(OUTP, CSUM, CSSQ);
  k_small3 <<<16,   128, 0, stream>>>(CSUM, CSSQ, gn_g, gn_b, se_w1, se_b1, se_w2, se_b2, SCA, SHB);
  k_final  <<<4096, 256, 0, stream>>>(OUTP, x, SCA, SHB, bias, iscale, out);
}

// Round 3
// 638.689 us; speedup vs baseline: 3.8027x; 3.8027x over previous
//
#include <hip/hip_runtime.h>
#include <hip/hip_bf16.h>
#include <math.h>

typedef __bf16 bf16_t;
typedef __bf16 bf16x8 __attribute__((ext_vector_type(8)));
typedef __bf16 bf16x4 __attribute__((ext_vector_type(4)));
typedef __bf16 bf16x2 __attribute__((ext_vector_type(2)));
typedef float  f32x4  __attribute__((ext_vector_type(4)));

#define EPSF 1e-5f
#define TAUF 1.5f

__device__ __forceinline__ float sigmoidf_(float x){ return 1.f/(1.f+__expf(-x)); }
__device__ __forceinline__ float siluf_(float x){ return x*sigmoidf_(x); }

// async global->LDS, 16B per lane; LDS dest = wave-uniform base + lane*16
__device__ __forceinline__ void gload_lds16(const void* g, void* l){
  __builtin_amdgcn_global_load_lds((const __attribute__((address_space(1))) unsigned int*)g,
                                   (__attribute__((address_space(3))) unsigned int*)l, 16, 0, 0);
}

// ---------------- p[b,c] = mean_hw(x) ----------------
__global__ void k_pool(const float* __restrict__ x, float* __restrict__ p){
  int bc = blockIdx.x; const float* xr = x + (size_t)bc*4096;
  float s = 0.f;
  for (int i = threadIdx.x; i < 4096; i += 256) s += xr[i];
  __shared__ float sb[4];
  for (int off=32; off; off>>=1) s += __shfl_down(s, off);
  if ((threadIdx.x & 63)==0) sb[threadIdx.x>>6] = s;
  __syncthreads();
  if (threadIdx.x==0) p[bc] = (sb[0]+sb[1]+sb[2]+sb[3]) * (1.f/4096.f);
}

// ---------------- per-b tiny MLPs ----------------
__global__ void k_small1(const float* __restrict__ p, const float* __restrict__ gc_w1,
                         const float* __restrict__ gc_w2, const float* __restrict__ cg_w1,
                         const float* __restrict__ cg_b1, const float* __restrict__ cg_w2,
                         const float* __restrict__ cg_b2,
                         float* __restrict__ gbuf, float* __restrict__ gate){
  int b = blockIdx.x; int t = threadIdx.x; // 128 threads
  __shared__ float ps[128], h1[32], pc[128], c1[16];
  ps[t] = p[b*128+t];
  __syncthreads();
  if (t < 32){ float a=0.f; for(int c=0;c<128;c++) a += ps[c]*gc_w1[t*128+c]; h1[t]=siluf_(a); }
  __syncthreads();
  float a=0.f; for(int j=0;j<32;j++) a += h1[j]*gc_w2[t*32+j];
  float g = sigmoidf_(a);
  gbuf[b*128+t] = g; pc[t] = ps[t]*g;   // mean(x*g) = g*mean(x)
  __syncthreads();
  if (t < 16){ float a2=cg_b1[t]; for(int c=0;c<128;c++) a2 += pc[c]*cg_w1[t*128+c]; c1[t]=siluf_(a2); }
  __syncthreads();
  float a3=cg_b2[t]; for(int j=0;j<16;j++) a3 += c1[j]*cg_w2[t*16+j];
  gate[b*128+t] = g * sigmoidf_(a3);
}

// ---------------- s_in: mean/max over channels of x*g ----------------
__global__ void k_spatial(const float* __restrict__ x, const float* __restrict__ gbuf,
                          float* __restrict__ sin_){
  int bi = blockIdx.x; int b = bi>>4; int h = ((bi&15)<<2) + (threadIdx.x>>6); int w = threadIdx.x&63;
  float sm=0.f, mx=-1e30f;
  for (int c=0;c<128;c++){
    float v = x[(((size_t)(b*128+c))*64 + h)*64 + w] * gbuf[b*128+c];
    sm += v; mx = fmaxf(mx, v);
  }
  sin_[b*8192 + h*64 + w]        = sm*(1.f/128.f);
  sin_[b*8192 + 4096 + h*64 + w] = mx;
}

// ---------------- 7x7 spatial-gate conv ----------------
__global__ void k_sgconv(const float* __restrict__ sin_, const float* __restrict__ sg_w,
                         float* __restrict__ satt){
  int bi = blockIdx.x; int b = bi>>4; int h = ((bi&15)<<2)+(threadIdx.x>>6); int w = threadIdx.x&63;
  float a = 0.f;
  for (int c2=0;c2<2;c2++){
    const float* sp = sin_ + b*8192 + c2*4096;
    const float* wp = sg_w + c2*49;
    for (int di=0;di<7;di++){ int hh=h+di-3; if (hh<0||hh>=64) continue;
      for (int dj=0;dj<7;dj++){ int ww=w+dj-3; if (ww<0||ww>=64) continue;
        a += sp[hh*64+ww]*wp[di*7+dj]; } }
  }
  satt[b*4096 + h*64 + w] = sigmoidf_(a);
}

// ---------------- zero X2T borders (padded layout, 4 ch-planes/b) ----------------
__global__ void k_zb(bf16_t* __restrict__ x2t){
  int p = blockIdx.x; // 0..63 = b*4+h2
  for (int i = threadIdx.x; i < 260; i += 256){
    int hp, wp;
    if (i < 66){ hp = 0; wp = i; }
    else if (i < 132){ hp = 65; wp = i-66; }
    else if (i < 196){ hp = i-131; wp = 0; }
    else { hp = i-195; wp = 65; }
    float4* dst = (float4*)(x2t + (((size_t)p*66 + hp)*66 + wp)*32);
    float4 z = {0.f,0.f,0.f,0.f};
    dst[0]=z; dst[1]=z; dst[2]=z; dst[3]=z;
  }
}

// ---------------- x2 = x*g*c_attn*s_attn -> half-split channels-last padded bf16 ----------------
// X2T layout: [b][h2(4)][hp(66)][wp(66)][32ch]
__global__ void k_x2(const float* __restrict__ x, const float* __restrict__ gate,
                     const float* __restrict__ satt, bf16_t* __restrict__ x2t,
                     float* __restrict__ pc2){
  int bi = blockIdx.x; int b = bi>>6; int h = bi&63;
  __shared__ bf16_t tile[128*66];
  int wv = threadIdx.x>>6, lane = threadIdx.x&63;
  float sa = satt[b*4096 + h*64 + lane];
  for (int it=0; it<32; it++){
    int c = it*4 + wv;
    float v = x[(((size_t)(b*128+c))*64 + h)*64 + lane] * gate[b*128+c] * sa;
    tile[c*66 + lane] = (bf16_t)v;
    float s = v;
    for (int off=32; off; off>>=1) s += __shfl_down(s, off);
    if (lane==0) atomicAdd(&pc2[b*128+c], s);
  }
  __syncthreads();
  for (int it=0; it<16; it++){
    int idx = it*256 + threadIdx.x;
    int w = idx>>6; int cp = idx&63; int c = cp*2;
    bf16x2 v; v[0] = tile[c*66 + w]; v[1] = tile[(c+1)*66 + w];
    *(bf16x2*)(x2t + (((size_t)(b*4 + (c>>5))*66 + (h+1))*66 + (w+1))*32 + (c&31)) = v;
  }
}

// ---------------- gf = silu(mean(x2) @ rg_w^T) ----------------
__global__ void k_small2(const float* __restrict__ pc2, const float* __restrict__ rg_w,
                         float* __restrict__ gf){
  int b = blockIdx.x; int t = threadIdx.x;
  if (t < 32){
    float a=0.f; for(int c=0;c<128;c++) a += pc2[b*128+c]*(1.f/4096.f)*rg_w[t*128+c];
    gf[b*32+t] = siluf_(a);
  }
}

// ---------------- weight prep: WC[(s*128+o)][t*128+c] bf16, RCW2[t][c][hid] f32 ----------------
__global__ void k_wprep(const float* __restrict__ base_w, const float* __restrict__ delta_w,
                        const float* __restrict__ kscale, const float* __restrict__ rc_w,
                        bf16_t* __restrict__ WC, float* __restrict__ RCW2){
  int i = blockIdx.x*256 + threadIdx.x;
  if (i < 640*1152){
    int r = i/1152; int kk = i - r*1152; int t = kk>>7; int c = kk&127;
    int s = r>>7; int o = r&127;
    float v;
    if (s==0) v = base_w[(o*128+c)*9 + t];
    else { int k = s-1; v = delta_w[(((k*128)+o)*128 + c)*9 + t] * kscale[k*128+o]; }
    WC[i] = (bf16_t)v;
  } else {
    int i2 = i - 640*1152;
    if (i2 < 9*128*32){
      int t = i2>>12; int c = (i2>>5)&127; int hid = i2&31;
      RCW2[i2] = rc_w[(hid*128+c)*9 + t];
    }
  }
}

// ---------------- router: lf = silu(BN(dilated conv(x2))) + gf -> bf16 channels-last ----------------
__global__ void __launch_bounds__(256) k_router(
    const bf16_t* __restrict__ x2t, const float* __restrict__ RCW2,
    const float* __restrict__ bn_gamma, const float* __restrict__ bn_beta,
    const float* __restrict__ bn_mean, const float* __restrict__ bn_var,
    const float* __restrict__ gf, bf16_t* __restrict__ lfb){
  int bi = blockIdx.x; int b = bi>>6; int h = bi&63;
  int w = threadIdx.x&63; int hg = threadIdx.x>>6;
  float acc[8]; for(int j=0;j<8;j++) acc[j]=0.f;
  for (int t=0;t<9;t++){
    int di=t/3, dj=t-di*3;
    int hs = h + 2*di - 1; if (hs<0||hs>65) continue;
    int ws = w + 2*dj - 1; if (ws<0||ws>65) continue;
    for (int h2=0;h2<4;h2++){
      const bf16_t* xp = x2t + (((size_t)(b*4+h2)*66 + hs)*66 + ws)*32;
      const float*  wp = RCW2 + t*4096 + h2*1024 + hg*8;
      #pragma unroll
      for (int c8=0;c8<4;c8++){
        bf16x8 xv = *(const bf16x8*)(xp + c8*8);
        #pragma unroll
        for (int e=0;e<8;e++){
          float xf = (float)xv[e];
          const float* wr = wp + (c8*8+e)*32;
          float4 w0 = *(const float4*)(wr);
          float4 w1 = *(const float4*)(wr+4);
          acc[0]+=xf*w0.x; acc[1]+=xf*w0.y; acc[2]+=xf*w0.z; acc[3]+=xf*w0.w;
          acc[4]+=xf*w1.x; acc[5]+=xf*w1.y; acc[6]+=xf*w1.z; acc[7]+=xf*w1.w;
        }
      }
    }
  }
  bf16x8 ov;
  #pragma unroll
  for (int j=0;j<8;j++){
    int hid = hg*8 + j;
    float aa = bn_gamma[hid]*rsqrtf(bn_var[hid]+EPSF);
    float bb = bn_beta[hid] - bn_mean[hid]*aa;
    ov[j] = (bf16_t)(siluf_(aa*acc[j]+bb) + gf[b*32+hid]);
  }
  *(bf16x8*)(lfb + ((size_t)b*4096 + h*64 + w)*32 + hg*8) = ov;
}

// ---------------- main dynamic conv: strip-resident implicit GEMM ----------------
// grid: 1024 = b(16) x hb(8 rows of 8) x ob(8 o-tiles of 16)
// per block: M=512 (8 rows x 64 w), N=80 (5 segs x 16 o), K=1152 (4 ch-halves x 9 taps x 32)
__global__ void __launch_bounds__(256, 2) k_main(
    const bf16_t* __restrict__ x2t, const bf16_t* __restrict__ WC,
    const bf16_t* __restrict__ lfb, const float* __restrict__ gate_w,
    const float* __restrict__ gate_b, bf16_t* __restrict__ outp,
    float* __restrict__ csum, float* __restrict__ cssq){
  __shared__ __align__(16) char smem[53248];
  bf16_t* strip = (bf16_t*)smem;                    // [10][66][32] = 42240 B
  // weight double-buffer lives at smem+42240 (+5120 per buffer)
  float*  sred  = (float*)(smem + 52480);           // 128 floats
  bf16_t* shLF  = (bf16_t*)smem;                    // epi: [512][32] = 32768 B
  bf16_t* shGW  = (bf16_t*)(smem + 42240);          // epi: [64][32] = 4096 B

  int tid = threadIdx.x;
  int wv = tid>>6, lane = tid&63, m16 = lane&15, q = lane>>4;
  int bx = blockIdx.x;
  int ob = bx & 7, hb = (bx>>3) & 7, b = bx>>6;
  int h0 = hb*8, obase = ob*16;

  f32x4 acc[8][5] = {};

  int baseA[8];
  #pragma unroll
  for (int mi=0;mi<8;mi++)
    baseA[mi] = (((wv*2 + (mi>>2))*66) + (mi&3)*16 + m16)*64 + q*16;
  int baseB = m16*64 + q*16;

  #pragma unroll 1
  for (int h2=0; h2<4; h2++){
    // stage A strip (42240 B) for this channel-half
    const char* asrc = (const char*)(x2t + (((size_t)(b*4 + h2)*66 + h0)*66)*32);
    for (int i = wv; i < 42; i += 4){
      if (i*1024 + lane*16 < 42240)
        gload_lds16(asrc + i*1024 + lane*16, (char*)smem + i*1024);
    }
    // stage B(t=0)
    for (int i = wv; i < 5; i += 4){
      int rr = i*16 + (lane>>2);
      int R = (rr>>4)*128 + obase + (rr&15);
      gload_lds16((const char*)(WC + (size_t)R*1152 + h2*32) + (lane&3)*16,
                  (char*)smem + 42240 + i*1024);
    }
    __syncthreads();
    #pragma unroll 1
    for (int t=0; t<9; t++){
      const char* Bcur = smem + 42240 + (t&1)*5120;
      if (t < 8){
        char* Bnext = smem + 42240 + ((t+1)&1)*5120;
        int tn = t+1;
        for (int i = wv; i < 5; i += 4){
          int rr = i*16 + (lane>>2);
          int R = (rr>>4)*128 + obase + (rr&15);
          gload_lds16((const char*)(WC + (size_t)R*1152 + tn*128 + h2*32) + (lane&3)*16,
                      Bnext + i*1024);
        }
      }
      int di = t/3, dj = t - di*3;
      int toff = (di*66 + dj)*64;
      bf16x8 av[8], bv[5];
      #pragma unroll
      for (int mi=0;mi<8;mi++) av[mi] = *(const bf16x8*)((const char*)strip + baseA[mi] + toff);
      #pragma unroll
      for (int s=0;s<5;s++)  bv[s] = *(const bf16x8*)(Bcur + baseB + s*1024);
      #pragma unroll
      for (int s=0;s<5;s++){
        #pragma unroll
        for (int mi=0;mi<8;mi++)
          acc[mi][s] = __builtin_amdgcn_mfma_f32_16x16x32_bf16(av[mi], bv[s], acc[mi][s], 0,0,0);
      }
      __syncthreads();
    }
  }

  // ---- epilogue: gate logits (4 tiny MFMAs/m-tile) + softmax + combine + GN-stats ----
  const char* lfsrc = (const char*)(lfb + ((size_t)b*4096 + h0*64)*32);
  for (int i = wv; i < 32; i += 4)
    gload_lds16(lfsrc + i*1024 + lane*16, (char*)smem + i*1024);
  for (int idx = tid; idx < 2048; idx += 256){
    int n = idx>>5, j = idx&31;
    shGW[n*32+j] = (bf16_t)gate_w[((n>>4)*128 + obase + (n&15))*32 + j];
  }
  __syncthreads();

  bf16x8 bg[4];
  #pragma unroll
  for (int kk=0;kk<4;kk++) bg[kk] = *(const bf16x8*)((const char*)shGW + (kk*16+m16)*64 + q*16);
  float gb[4];
  #pragma unroll
  for (int kk=0;kk<4;kk++) gb[kk] = gate_b[kk*128 + obase + m16];

  const float itau = 1.f/TAUF;
  float s1 = 0.f, s2 = 0.f;
  size_t orow = ((size_t)(b*128 + obase + m16))*4096 + h0*64;
  #pragma unroll
  for (int mi=0; mi<8; mi++){
    bf16x8 avL = *(const bf16x8*)((const char*)shLF + (wv*128 + mi*16 + m16)*64 + q*16);
    f32x4 zero = {};
    f32x4 lg[4];
    #pragma unroll
    for (int kk=0;kk<4;kk++)
      lg[kk] = __builtin_amdgcn_mfma_f32_16x16x32_bf16(avL, bg[kk], zero, 0,0,0);
    bf16x4 yv;
    #pragma unroll
    for (int r=0;r<4;r++){
      float l0 = (lg[0][r]+gb[0])*itau, l1 = (lg[1][r]+gb[1])*itau;
      float l2 = (lg[2][r]+gb[2])*itau, l3 = (lg[3][r]+gb[3])*itau;
      float mx = fmaxf(fmaxf(l0,l1),fmaxf(l2,l3));
      float e0=__expf(l0-mx), e1=__expf(l1-mx), e2=__expf(l2-mx), e3=__expf(l3-mx);
      float inv = 1.f/(e0+e1+e2+e3);
      float y = acc[mi][0][r] + (e0*acc[mi][1][r] + e1*acc[mi][2][r]
              + e2*acc[mi][3][r] + e3*acc[mi][4][r])*inv;
      s1 += y; s2 += y*y;
      yv[r] = (bf16_t)y;
    }
    *(bf16x4*)(outp + orow + wv*128 + mi*16 + q*4) = yv;
  }

  s1 += __shfl_down(s1, 32); s1 += __shfl_down(s1, 16);
  s2 += __shfl_down(s2, 32); s2 += __shfl_down(s2, 16);
  if (lane < 16){ sred[wv*16 + lane] = s1; sred[64 + wv*16 + lane] = s2; }
  __syncthreads();
  if (tid < 16){
    float a = sred[tid] + sred[16+tid] + sred[32+tid] + sred[48+tid];
    float c = sred[64+tid] + sred[80+tid] + sred[96+tid] + sred[112+tid];
    atomicAdd(&csum[b*128 + obase + tid], a);
    atomicAdd(&cssq[b*128 + obase + tid], c);
  }
}

// ---------------- GroupNorm stats + output-SE -> per-(b,o) affine ----------------
__global__ void k_small3(const float* __restrict__ csum, const float* __restrict__ cssq,
                         const float* __restrict__ gn_gamma, const float* __restrict__ gn_beta,
                         const float* __restrict__ se_w1, const float* __restrict__ se_b1,
                         const float* __restrict__ se_w2, const float* __restrict__ se_b2,
                         float* __restrict__ sca, float* __restrict__ shb){
  int b = blockIdx.x; int o = threadIdx.x; // 128
  __shared__ float s1[128], s2[128], gmu[8], grs[8], psl[128], t1[16];
  s1[o] = csum[b*128+o]; s2[o] = cssq[b*128+o];
  __syncthreads();
  if (o<8){
    float a=0.f,a2=0.f; for(int j=0;j<16;j++){ a+=s1[o*16+j]; a2+=s2[o*16+j]; }
    float mu = a*(1.f/65536.f); float var = a2*(1.f/65536.f) - mu*mu;
    gmu[o]=mu; grs[o]=rsqrtf(var+EPSF);
  }
  __syncthreads();
  int g = o>>4;
  psl[o] = (s1[o]*(1.f/4096.f) - gmu[g])*grs[g]*gn_gamma[o] + gn_beta[o];
  __syncthreads();
  if (o<16){ float a = se_b1[o]; for(int c=0;c<128;c++) a += psl[c]*se_w1[o*128+c]; t1[o]=siluf_(a); }
  __syncthreads();
  float a = se_b2[o]; for(int j=0;j<16;j++) a += t1[j]*se_w2[o*16+j];
  float sev = sigmoidf_(a);
  sca[b*128+o] = grs[g]*gn_gamma[o]*sev;
  shb[b*128+o] = (gn_beta[o] - gmu[g]*grs[g]*gn_gamma[o])*sev;
}

// ---------------- final: GN-affine*SE + tanh(identity_scale)*x + bias ----------------
__global__ void k_final(const bf16_t* __restrict__ outp, const float* __restrict__ x,
                        const float* __restrict__ sca, const float* __restrict__ shb,
                        const float* __restrict__ bias, const float* __restrict__ iscale,
                        float* __restrict__ out){
  float ts = tanhf(iscale[0]);
  size_t i = ((size_t)blockIdx.x*256 + threadIdx.x)*8;
  int bo = (int)(i>>12); int o = bo&127;
  float A = sca[bo], Bv = shb[bo] + bias[o];
  bf16x8 ov = *(const bf16x8*)(outp + i);
  float4 x0 = *(const float4*)(x+i), x1 = *(const float4*)(x+i+4);
  float4 r0, r1;
  r0.x = (float)ov[0]*A + Bv + ts*x0.x;
  r0.y = (float)ov[1]*A + Bv + ts*x0.y;
  r0.z = (float)ov[2]*A + Bv + ts*x0.z;
  r0.w = (float)ov[3]*A + Bv + ts*x0.w;
  r1.x = (float)ov[4]*A + Bv + ts*x1.x;
  r1.y = (float)ov[5]*A + Bv + ts*x1.y;
  r1.z = (float)ov[6]*A + Bv + ts*x1.z;
  r1.w = (float)ov[7]*A + Bv + ts*x1.w;
  *(float4*)(out+i) = r0; *(float4*)(out+i+4) = r1;
}

extern "C" void kernel_launch(void* const* d_in, const int* in_sizes, int n_in,
                              void* d_out, int out_size, void* d_ws, size_t ws_size,
                              hipStream_t stream){
  const float* x      = (const float*)d_in[0];
  const float* base_w = (const float*)d_in[1];
  const float* delta_w= (const float*)d_in[2];
  const float* kscale = (const float*)d_in[3];
  const float* gc_w1  = (const float*)d_in[4];
  const float* gc_w2  = (const float*)d_in[5];
  const float* rc_w   = (const float*)d_in[6];
  const float* bn_g   = (const float*)d_in[7];
  const float* bn_b   = (const float*)d_in[8];
  const float* bn_m   = (const float*)d_in[9];
  const float* bn_v   = (const float*)d_in[10];
  const float* rg_w   = (const float*)d_in[11];
  const float* gate_w = (const float*)d_in[12];
  const float* gate_b = (const float*)d_in[13];
  const float* cg_w1  = (const float*)d_in[14];
  const float* cg_b1  = (const float*)d_in[15];
  const float* cg_w2  = (const float*)d_in[16];
  const float* cg_b2  = (const float*)d_in[17];
  const float* sg_w   = (const float*)d_in[18];
  const float* gn_g   = (const float*)d_in[19];
  const float* gn_b   = (const float*)d_in[20];
  const float* se_w1  = (const float*)d_in[21];
  const float* se_b1  = (const float*)d_in[22];
  const float* se_w2  = (const float*)d_in[23];
  const float* se_b2  = (const float*)d_in[24];
  const float* iscale = (const float*)d_in[25];
  const float* bias   = (const float*)d_in[26];
  float* out = (float*)d_out;

  char* ws = (char*)d_ws;
  size_t off = 0;
  auto alloc = [&](size_t bytes)->void*{ void* p = ws + off; off += (bytes + 255) & ~(size_t)255; return p; };
  bf16_t* X2T = (bf16_t*)alloc(16ull*4*66*66*32*2);  // half-split padded channels-last
  bf16_t* WC  = (bf16_t*)alloc(640ull*1152*2);
  float* RCW2 = (float*)alloc(9ull*128*32*4);
  bf16_t* LF  = (bf16_t*)alloc(16ull*4096*32*2);
  bf16_t* OUTP= (bf16_t*)alloc(16ull*128*4096*2);
  float* PC2  = (float*)alloc(2048*4);               // PC2+CSUM+CSSQ contiguous
  float* CSUM = (float*)alloc(2048*4);
  float* CSSQ = (float*)alloc(2048*4);
  float* P    = (float*)alloc(2048*4);
  float* GB   = (float*)alloc(2048*4);
  float* GATE = (float*)alloc(2048*4);
  float* GF   = (float*)alloc(512*4);
  float* SIN  = (float*)alloc(16ull*8192*4);
  float* SATT = (float*)alloc(16ull*4096*4);
  float* SCA  = (float*)alloc(2048*4);
  float* SHB  = (float*)alloc(2048*4);

  (void)hipMemsetAsync(PC2, 0, 3*8192, stream);  // PC2, CSUM, CSSQ

  k_wprep  <<<3024, 256, 0, stream>>>(base_w, delta_w, kscale, rc_w, WC, RCW2);
  k_pool   <<<2048, 256, 0, stream>>>(x, P);
  k_small1 <<<16,   128, 0, stream>>>(P, gc_w1, gc_w2, cg_w1, cg_b1, cg_w2, cg_b2, GB, GATE);
  k_spatial<<<256,  256, 0, stream>>>(x, GB, SIN);
  k_sgconv <<<256,  256, 0, stream>>>(SIN, sg_w, SATT);
  k_zb     <<<64,   256, 0, stream>>>(X2T);
  k_x2     <<<1024, 256, 0, stream>>>(x, GATE, SATT, X2T, PC2);
  k_small2 <<<16,    64, 0, stream>>>(PC2, rg_w, GF);
  k_router <<<1024, 256, 0, stream>>>(X2T, RCW2, bn_g, bn_b, bn_m, bn_v, GF, LF);
  k_main   <<<1024, 256, 0, stream>>>(X2T, WC, LF, gate_w, gate_b, OUTP, CSUM, CSSQ);
  k_small3 <<<16,   128, 0, stream>>>(CSUM, CSSQ, gn_g, gn_b, se_w1, se_b1, se_w2, se_b2, SCA, SHB);
  k_final  <<<4096, 256, 0, stream>>>(OUTP, x, SCA, SHB, bias, iscale, out);
}

// Round 4
// 367.902 us; speedup vs baseline: 6.6015x; 1.7360x over previous
//
#include <hip/hip_runtime.h>
#include <hip/hip_bf16.h>
#include <math.h>

typedef __bf16 bf16_t;
typedef __bf16 bf16x8 __attribute__((ext_vector_type(8)));
typedef __bf16 bf16x4 __attribute__((ext_vector_type(4)));
typedef __bf16 bf16x2 __attribute__((ext_vector_type(2)));
typedef float  f32x4  __attribute__((ext_vector_type(4)));

#define EPSF 1e-5f
#define TAUF 1.5f

__device__ __forceinline__ float sigmoidf_(float x){ return 1.f/(1.f+__expf(-x)); }
__device__ __forceinline__ float siluf_(float x){ return x*sigmoidf_(x); }

// async global->LDS, 16B per lane; LDS dest = wave-uniform base + lane*16
__device__ __forceinline__ void gload_lds16(const void* g, void* l){
  __builtin_amdgcn_global_load_lds((const __attribute__((address_space(1))) unsigned int*)g,
                                   (__attribute__((address_space(3))) unsigned int*)l, 16, 0, 0);
}

// ---------------- p[b,c] = mean_hw(x) ----------------
__global__ void k_pool(const float* __restrict__ x, float* __restrict__ p){
  int bc = blockIdx.x; const float* xr = x + (size_t)bc*4096;
  float s = 0.f;
  for (int i = threadIdx.x; i < 4096; i += 256) s += xr[i];
  __shared__ float sb[4];
  for (int off=32; off; off>>=1) s += __shfl_down(s, off);
  if ((threadIdx.x & 63)==0) sb[threadIdx.x>>6] = s;
  __syncthreads();
  if (threadIdx.x==0) p[bc] = (sb[0]+sb[1]+sb[2]+sb[3]) * (1.f/4096.f);
}

// ---------------- per-b tiny MLPs ----------------
__global__ void k_small1(const float* __restrict__ p, const float* __restrict__ gc_w1,
                         const float* __restrict__ gc_w2, const float* __restrict__ cg_w1,
                         const float* __restrict__ cg_b1, const float* __restrict__ cg_w2,
                         const float* __restrict__ cg_b2,
                         float* __restrict__ gbuf, float* __restrict__ gate){
  int b = blockIdx.x; int t = threadIdx.x; // 128 threads
  __shared__ float ps[128], h1[32], pc[128], c1[16];
  ps[t] = p[b*128+t];
  __syncthreads();
  if (t < 32){ float a=0.f; for(int c=0;c<128;c++) a += ps[c]*gc_w1[t*128+c]; h1[t]=siluf_(a); }
  __syncthreads();
  float a=0.f; for(int j=0;j<32;j++) a += h1[j]*gc_w2[t*32+j];
  float g = sigmoidf_(a);
  gbuf[b*128+t] = g; pc[t] = ps[t]*g;   // mean(x*g) = g*mean(x)
  __syncthreads();
  if (t < 16){ float a2=cg_b1[t]; for(int c=0;c<128;c++) a2 += pc[c]*cg_w1[t*128+c]; c1[t]=siluf_(a2); }
  __syncthreads();
  float a3=cg_b2[t]; for(int j=0;j<16;j++) a3 += c1[j]*cg_w2[t*16+j];
  gate[b*128+t] = g * sigmoidf_(a3);
}

// ---------------- s_in: mean/max over channels of x*g ----------------
__global__ void k_spatial(const float* __restrict__ x, const float* __restrict__ gbuf,
                          float* __restrict__ sin_){
  int bi = blockIdx.x; int b = bi>>4; int h = ((bi&15)<<2) + (threadIdx.x>>6); int w = threadIdx.x&63;
  float sm=0.f, mx=-1e30f;
  for (int c=0;c<128;c++){
    float v = x[(((size_t)(b*128+c))*64 + h)*64 + w] * gbuf[b*128+c];
    sm += v; mx = fmaxf(mx, v);
  }
  sin_[b*8192 + h*64 + w]        = sm*(1.f/128.f);
  sin_[b*8192 + 4096 + h*64 + w] = mx;
}

// ---------------- 7x7 spatial-gate conv ----------------
__global__ void k_sgconv(const float* __restrict__ sin_, const float* __restrict__ sg_w,
                         float* __restrict__ satt){
  int bi = blockIdx.x; int b = bi>>4; int h = ((bi&15)<<2)+(threadIdx.x>>6); int w = threadIdx.x&63;
  float a = 0.f;
  for (int c2=0;c2<2;c2++){
    const float* sp = sin_ + b*8192 + c2*4096;
    const float* wp = sg_w + c2*49;
    for (int di=0;di<7;di++){ int hh=h+di-3; if (hh<0||hh>=64) continue;
      for (int dj=0;dj<7;dj++){ int ww=w+dj-3; if (ww<0||ww>=64) continue;
        a += sp[hh*64+ww]*wp[di*7+dj]; } }
  }
  satt[b*4096 + h*64 + w] = sigmoidf_(a);
}

// ---------------- zero X2Q borders (2-halo, 256 planes of [68][68][8]) ----------------
__global__ void k_zb(bf16_t* __restrict__ x2q){
  size_t base = (size_t)blockIdx.x*68*68*8;
  float4 z = {0.f,0.f,0.f,0.f};
  // rows 0,1,66,67 full width
  for (int i = threadIdx.x; i < 272; i += 256){
    int r = i/68; int wp = i - r*68;
    int hp = (r&1) + (r>>1)*66;
    *(float4*)(x2q + base + ((size_t)hp*68 + wp)*8) = z;
  }
  // cols 0,1,66,67 rows 2..65
  {
    int i = threadIdx.x; // exactly 256 items
    int hp = 2 + (i>>2);
    int wp = (i&1) + (i&2)*33;
    *(float4*)(x2q + base + ((size_t)hp*68 + wp)*8) = z;
  }
}

// ---------------- x2 = x*g*c_attn*s_attn -> quad-split channels-last padded bf16 ----------------
// X2Q layout: [b][h2(4)][q(4)][68][68][8ch], original (h,w) at padded (h+2, w+2)
__global__ void k_x2(const float* __restrict__ x, const float* __restrict__ gate,
                     const float* __restrict__ satt, bf16_t* __restrict__ x2q,
                     float* __restrict__ pc2){
  int bi = blockIdx.x; int b = bi>>6; int h = bi&63;
  __shared__ bf16_t tile[128*66];
  int wv = threadIdx.x>>6, lane = threadIdx.x&63;
  float sa = satt[b*4096 + h*64 + lane];
  for (int it=0; it<32; it++){
    int c = it*4 + wv;
    float v = x[(((size_t)(b*128+c))*64 + h)*64 + lane] * gate[b*128+c] * sa;
    tile[c*66 + lane] = (bf16_t)v;
    float s = v;
    for (int off=32; off; off>>=1) s += __shfl_down(s, off);
    if (lane==0) atomicAdd(&pc2[b*128+c], s);
  }
  __syncthreads();
  for (int it=0; it<4; it++){
    int idx = it*256 + threadIdx.x;      // 1024 items: cq(16) x w(64)
    int cq = idx>>6; int w = idx&63;
    int c0 = cq*8;
    bf16x8 v;
    #pragma unroll
    for (int e=0;e<8;e++) v[e] = tile[(c0+e)*66 + w];
    *(bf16x8*)(x2q + (((((size_t)b*4 + (cq>>2))*4 + (cq&3))*68 + (h+2))*68 + (w+2))*8) = v;
  }
}

// ---------------- gf = silu(mean(x2) @ rg_w^T) ----------------
__global__ void k_small2(const float* __restrict__ pc2, const float* __restrict__ rg_w,
                         float* __restrict__ gf){
  int b = blockIdx.x; int t = threadIdx.x;
  if (t < 32){
    float a=0.f; for(int c=0;c<128;c++) a += pc2[b*128+c]*(1.f/4096.f)*rg_w[t*128+c];
    gf[b*32+t] = siluf_(a);
  }
}

// ---------------- weight prep ----------------
// WCQ  [ob(8)][t(9)][h2(4)][s(5)][q(4)][o16(16)][c8(8)] bf16
// RCWQ [t(9)][h2(4)][n2(2)][q(4)][h16(16)][c8(8)] bf16
__global__ void k_wprep(const float* __restrict__ base_w, const float* __restrict__ delta_w,
                        const float* __restrict__ kscale, const float* __restrict__ rc_w,
                        bf16_t* __restrict__ WCQ, bf16_t* __restrict__ RCWQ){
  int i = blockIdx.x*256 + threadIdx.x;
  if (i < 737280){
    int c8 = i&7; int i1 = i>>3;
    int o16 = i1&15; int i2 = i1>>4;
    int q = i2&3; int i3 = i2>>2;
    int s = i3%5; int i4 = i3/5;
    int h2 = i4&3; int i5 = i4>>2;
    int t = i5%9; int ob = i5/9;
    int o = ob*16 + o16; int c = h2*32 + q*8 + c8;
    float v;
    if (s==0) v = base_w[(o*128+c)*9 + t];
    else { int k = s-1; v = delta_w[(((k*128)+o)*128 + c)*9 + t] * kscale[k*128+o]; }
    WCQ[i] = (bf16_t)v;
  } else {
    int j = i - 737280;  // < 36864
    int c8 = j&7; int h16 = (j>>3)&15; int q = (j>>7)&3;
    int n2 = (j>>9)&1; int h2 = (j>>10)&3; int t = j>>12;
    int hid = n2*16 + h16; int c = h2*32 + q*8 + c8;
    RCWQ[j] = (bf16_t)rc_w[(hid*128+c)*9 + t];
  }
}

// ---------------- router: MFMA strip kernel ----------------
// grid 256 = b(16) x hb(16 strips of 4 rows). M=256 pos, N=32 hid, K=1152.
// A-operand = weights (M=hid per-tile), B-operand = strip positions.
__global__ void __launch_bounds__(256) k_router(
    const bf16_t* __restrict__ x2q, const bf16_t* __restrict__ RCWQ,
    const float* __restrict__ bn_gamma, const float* __restrict__ bn_beta,
    const float* __restrict__ bn_mean, const float* __restrict__ bn_var,
    const float* __restrict__ gf, bf16_t* __restrict__ lfb){
  __shared__ __align__(16) char smem[43008]; // strip 4x8704=34816 + B dbuf 2x4096
  int tid = threadIdx.x;
  int wv = tid>>6, lane = tid&63, m16 = lane&15, q = lane>>4;
  int hb = blockIdx.x & 15, b = blockIdx.x >> 4;
  int r0 = hb*4;

  f32x4 acc[2][4] = {};   // [n2][wseg]

  #pragma unroll 1
  for (int h2=0; h2<4; h2++){
    // stage strip: wave wv stages q-plane wv, padded rows r0..r0+7 (8 x 1088 B)
    const char* asrc = (const char*)(x2q + ((((size_t)(b*4+h2)*4 + wv)*68 + r0)*68)*8);
    #pragma unroll
    for (int j=0;j<9;j++){
      if (j*64 + lane < 544)
        gload_lds16(asrc + j*1024 + lane*16, (char*)smem + wv*8704 + j*1024);
    }
    // stage B(t=0)
    gload_lds16((const char*)(RCWQ + (size_t)(h2)*2048) + wv*1024 + lane*16,
                (char*)smem + 34816 + wv*1024);
    __syncthreads();
    #pragma unroll 1
    for (int t=0; t<9; t++){
      const char* Bcur = smem + 34816 + (t&1)*4096;
      if (t < 8){
        gload_lds16((const char*)(RCWQ + (size_t)((t+1)*4 + h2)*2048) + wv*1024 + lane*16,
                    (char*)smem + 34816 + ((t+1)&1)*4096 + wv*1024);
      }
      int di = t/3, dj = t - di*3;
      bf16x8 aw0 = *(const bf16x8*)(Bcur + q*256 + m16*16);
      bf16x8 aw1 = *(const bf16x8*)(Bcur + 1024 + q*256 + m16*16);
      int rbase = (wv + 2*di)*68 + 2*dj + m16;
      bf16x8 bs[4];
      #pragma unroll
      for (int ws=0;ws<4;ws++)
        bs[ws] = *(const bf16x8*)((const char*)smem + q*8704 + (rbase + ws*16)*16);
      #pragma unroll
      for (int ws=0;ws<4;ws++){
        acc[0][ws] = __builtin_amdgcn_mfma_f32_16x16x32_bf16(aw0, bs[ws], acc[0][ws], 0,0,0);
        acc[1][ws] = __builtin_amdgcn_mfma_f32_16x16x32_bf16(aw1, bs[ws], acc[1][ws], 0,0,0);
      }
      __syncthreads();
    }
  }

  // epilogue: BN + silu + gf, write bf16 channels-last
  #pragma unroll
  for (int n2=0;n2<2;n2++){
    float aa[4], bb[4];
    #pragma unroll
    for (int i=0;i<4;i++){
      int hid = n2*16 + q*4 + i;
      float a = bn_gamma[hid]*rsqrtf(bn_var[hid]+EPSF);
      aa[i] = a;
      bb[i] = bn_beta[hid] - bn_mean[hid]*a + 0.f;
    }
    #pragma unroll
    for (int ws=0;ws<4;ws++){
      bf16x4 yv;
      #pragma unroll
      for (int i=0;i<4;i++){
        int hid = n2*16 + q*4 + i;
        float v = siluf_(aa[i]*acc[n2][ws][i] + bb[i]) + gf[b*32+hid];
        yv[i] = (bf16_t)v;
      }
      size_t pos = (size_t)b*4096 + (r0+wv)*64 + ws*16 + m16;
      *(bf16x4*)(lfb + pos*32 + n2*16 + q*4) = yv;
    }
  }
}

// ---------------- main dynamic conv: strip-resident implicit GEMM (conflict-free) ----------------
// grid: 1024 = b(16) x hb(8 rows of 8) x ob(8 o-tiles of 16)
// M=512 (8 rows x 64 w), N=80 (5 segs x 16 o), K=1152 (4 ch-halves x 9 taps x 32)
__global__ void __launch_bounds__(256, 2) k_main(
    const bf16_t* __restrict__ x2q, const bf16_t* __restrict__ WCQ,
    const bf16_t* __restrict__ lfb, const float* __restrict__ gate_w,
    const float* __restrict__ gate_b, bf16_t* __restrict__ outp,
    float* __restrict__ csum, float* __restrict__ cssq){
  __shared__ __align__(16) char smem[54272];
  // strip: 4 q-planes x 10880B = 43520; B dbuf 2x5120 @43520; sred 512B @53760
  bf16_t* shGW  = (bf16_t*)(smem + 43520);  // epi: [64][32] = 4096 B
  float*  sred  = (float*)(smem + 53760);

  int tid = threadIdx.x;
  int wv = tid>>6, lane = tid&63, m16 = lane&15, q = lane>>4;
  int bx = blockIdx.x;
  int ob = bx & 7, hb = (bx>>3) & 7, b = bx>>6;
  int h0 = hb*8, obase = ob*16;

  f32x4 acc[8][5] = {};

  int baseA[8];
  #pragma unroll
  for (int mi=0;mi<8;mi++){
    int row = wv*2 + (mi>>2); int wseg = mi&3;
    baseA[mi] = (row*68 + wseg*16 + m16 + 1)*16 + q*10880;
  }
  int baseB = q*256 + m16*16;

  #pragma unroll 1
  for (int h2=0; h2<4; h2++){
    // stage strip: wave wv stages q-plane wv, padded rows h0+1..h0+10 (10 x 1088 B)
    const char* asrc = (const char*)(x2q + ((((size_t)(b*4+h2)*4 + wv)*68 + (h0+1))*68)*8);
    #pragma unroll
    for (int j=0;j<11;j++){
      if (j*64 + lane < 680)
        gload_lds16(asrc + j*1024 + lane*16, (char*)smem + wv*10880 + j*1024);
    }
    // stage B(t=0)
    {
      const char* bsrc = (const char*)(WCQ + ((size_t)(ob*9 + 0)*4 + h2)*2560);
      for (int s = wv; s < 5; s += 4)
        gload_lds16(bsrc + s*1024 + lane*16, (char*)smem + 43520 + s*1024);
    }
    __syncthreads();
    #pragma unroll 1
    for (int t=0; t<9; t++){
      const char* Bcur = smem + 43520 + (t&1)*5120;
      if (t < 8){
        const char* bsrc = (const char*)(WCQ + ((size_t)(ob*9 + (t+1))*4 + h2)*2560);
        char* Bnext = smem + 43520 + ((t+1)&1)*5120;
        for (int s = wv; s < 5; s += 4)
          gload_lds16(bsrc + s*1024 + lane*16, Bnext + s*1024);
      }
      int di = t/3, dj = t - di*3;
      int toff = (di*68 + dj)*16;
      bf16x8 av[8], bv[5];
      #pragma unroll
      for (int mi=0;mi<8;mi++) av[mi] = *(const bf16x8*)((const char*)smem + baseA[mi] + toff);
      #pragma unroll
      for (int s=0;s<5;s++)  bv[s] = *(const bf16x8*)(Bcur + s*1024 + baseB);
      #pragma unroll
      for (int s=0;s<5;s++){
        #pragma unroll
        for (int mi=0;mi<8;mi++)
          acc[mi][s] = __builtin_amdgcn_mfma_f32_16x16x32_bf16(av[mi], bv[s], acc[mi][s], 0,0,0);
      }
      __syncthreads();
    }
  }

  // ---- epilogue: gate logits (4 tiny MFMAs/m-tile) + softmax + combine + GN-stats ----
  const char* lfsrc = (const char*)(lfb + ((size_t)b*4096 + h0*64)*32);
  for (int i = wv; i < 32; i += 4)
    gload_lds16(lfsrc + i*1024 + lane*16, (char*)smem + i*1024);
  for (int idx = tid; idx < 2048; idx += 256){
    int n = idx>>5, j = idx&31;
    shGW[n*32+j] = (bf16_t)gate_w[((n>>4)*128 + obase + (n&15))*32 + j];
  }
  __syncthreads();

  bf16x8 bg[4];
  #pragma unroll
  for (int kk=0;kk<4;kk++) bg[kk] = *(const bf16x8*)((const char*)shGW + (kk*16+m16)*64 + q*16);
  float gb[4];
  #pragma unroll
  for (int kk=0;kk<4;kk++) gb[kk] = gate_b[kk*128 + obase + m16];

  const float itau = 1.f/TAUF;
  float s1 = 0.f, s2 = 0.f;
  size_t orow = ((size_t)(b*128 + obase + m16))*4096 + h0*64;
  #pragma unroll
  for (int mi=0; mi<8; mi++){
    bf16x8 avL = *(const bf16x8*)((const char*)smem + (wv*128 + mi*16 + m16)*64 + q*16);
    f32x4 zero = {};
    f32x4 lg[4];
    #pragma unroll
    for (int kk=0;kk<4;kk++)
      lg[kk] = __builtin_amdgcn_mfma_f32_16x16x32_bf16(avL, bg[kk], zero, 0,0,0);
    bf16x4 yv;
    #pragma unroll
    for (int r=0;r<4;r++){
      float l0 = (lg[0][r]+gb[0])*itau, l1 = (lg[1][r]+gb[1])*itau;
      float l2 = (lg[2][r]+gb[2])*itau, l3 = (lg[3][r]+gb[3])*itau;
      float mx = fmaxf(fmaxf(l0,l1),fmaxf(l2,l3));
      float e0=__expf(l0-mx), e1=__expf(l1-mx), e2=__expf(l2-mx), e3=__expf(l3-mx);
      float inv = 1.f/(e0+e1+e2+e3);
      float y = acc[mi][0][r] + (e0*acc[mi][1][r] + e1*acc[mi][2][r]
              + e2*acc[mi][3][r] + e3*acc[mi][4][r])*inv;
      s1 += y; s2 += y*y;
      yv[r] = (bf16_t)y;
    }
    *(bf16x4*)(outp + orow + wv*128 + mi*16 + q*4) = yv;
  }

  s1 += __shfl_down(s1, 32); s1 += __shfl_down(s1, 16);
  s2 += __shfl_down(s2, 32); s2 += __shfl_down(s2, 16);
  if (lane < 16){ sred[wv*16 + lane] = s1; sred[64 + wv*16 + lane] = s2; }
  __syncthreads();
  if (tid < 16){
    float a = sred[tid] + sred[16+tid] + sred[32+tid] + sred[48+tid];
    float c = sred[64+tid] + sred[80+tid] + sred[96+tid] + sred[112+tid];
    atomicAdd(&csum[b*128 + obase + tid], a);
    atomicAdd(&cssq[b*128 + obase + tid], c);
  }
}

// ---------------- GroupNorm stats + output-SE -> per-(b,o) affine ----------------
__global__ void k_small3(const float* __restrict__ csum, const float* __restrict__ cssq,
                         const float* __restrict__ gn_gamma, const float* __restrict__ gn_beta,
                         const float* __restrict__ se_w1, const float* __restrict__ se_b1,
                         const float* __restrict__ se_w2, const float* __restrict__ se_b2,
                         float* __restrict__ sca, float* __restrict__ shb){
  int b = blockIdx.x; int o = threadIdx.x; // 128
  __shared__ float s1[128], s2[128], gmu[8], grs[8], psl[128], t1[16];
  s1[o] = csum[b*128+o]; s2[o] = cssq[b*128+o];
  __syncthreads();
  if (o<8){
    float a=0.f,a2=0.f; for(int j=0;j<16;j++){ a+=s1[o*16+j]; a2+=s2[o*16+j]; }
    float mu = a*(1.f/65536.f); float var = a2*(1.f/65536.f) - mu*mu;
    gmu[o]=mu; grs[o]=rsqrtf(var+EPSF);
  }
  __syncthreads();
  int g = o>>4;
  psl[o] = (s1[o]*(1.f/4096.f) - gmu[g])*grs[g]*gn_gamma[o] + gn_beta[o];
  __syncthreads();
  if (o<16){ float a = se_b1[o]; for(int c=0;c<128;c++) a += psl[c]*se_w1[o*128+c]; t1[o]=siluf_(a); }
  __syncthreads();
  float a = se_b2[o]; for(int j=0;j<16;j++) a += t1[j]*se_w2[o*16+j];
  float sev = sigmoidf_(a);
  sca[b*128+o] = grs[g]*gn_gamma[o]*sev;
  shb[b*128+o] = (gn_beta[o] - gmu[g]*grs[g]*gn_gamma[o])*sev;
}

// ---------------- final: GN-affine*SE + tanh(identity_scale)*x + bias ----------------
__global__ void k_final(const bf16_t* __restrict__ outp, const float* __restrict__ x,
                        const float* __restrict__ sca, const float* __restrict__ shb,
                        const float* __restrict__ bias, const float* __restrict__ iscale,
                        float* __restrict__ out){
  float ts = tanhf(iscale[0]);
  size_t i = ((size_t)blockIdx.x*256 + threadIdx.x)*8;
  int bo = (int)(i>>12); int o = bo&127;
  float A = sca[bo], Bv = shb[bo] + bias[o];
  bf16x8 ov = *(const bf16x8*)(outp + i);
  float4 x0 = *(const float4*)(x+i), x1 = *(const float4*)(x+i+4);
  float4 r0, r1;
  r0.x = (float)ov[0]*A + Bv + ts*x0.x;
  r0.y = (float)ov[1]*A + Bv + ts*x0.y;
  r0.z = (float)ov[2]*A + Bv + ts*x0.z;
  r0.w = (float)ov[3]*A + Bv + ts*x0.w;
  r1.x = (float)ov[4]*A + Bv + ts*x1.x;
  r1.y = (float)ov[5]*A + Bv + ts*x1.y;
  r1.z = (float)ov[6]*A + Bv + ts*x1.z;
  r1.w = (float)ov[7]*A + Bv + ts*x1.w;
  *(float4*)(out+i) = r0; *(float4*)(out+i+4) = r1;
}

extern "C" void kernel_launch(void* const* d_in, const int* in_sizes, int n_in,
                              void* d_out, int out_size, void* d_ws, size_t ws_size,
                              hipStream_t stream){
  const float* x      = (const float*)d_in[0];
  const float* base_w = (const float*)d_in[1];
  const float* delta_w= (const float*)d_in[2];
  const float* kscale = (const float*)d_in[3];
  const float* gc_w1  = (const float*)d_in[4];
  const float* gc_w2  = (const float*)d_in[5];
  const float* rc_w   = (const float*)d_in[6];
  const float* bn_g   = (const float*)d_in[7];
  const float* bn_b   = (const float*)d_in[8];
  const float* bn_m   = (const float*)d_in[9];
  const float* bn_v   = (const float*)d_in[10];
  const float* rg_w   = (const float*)d_in[11];
  const float* gate_w = (const float*)d_in[12];
  const float* gate_b = (const float*)d_in[13];
  const float* cg_w1  = (const float*)d_in[14];
  const float* cg_b1  = (const float*)d_in[15];
  const float* cg_w2  = (const float*)d_in[16];
  const float* cg_b2  = (const float*)d_in[17];
  const float* sg_w   = (const float*)d_in[18];
  const float* gn_g   = (const float*)d_in[19];
  const float* gn_b   = (const float*)d_in[20];
  const float* se_w1  = (const float*)d_in[21];
  const float* se_b1  = (const float*)d_in[22];
  const float* se_w2  = (const float*)d_in[23];
  const float* se_b2  = (const float*)d_in[24];
  const float* iscale = (const float*)d_in[25];
  const float* bias   = (const float*)d_in[26];
  float* out = (float*)d_out;

  char* ws = (char*)d_ws;
  size_t off = 0;
  auto alloc = [&](size_t bytes)->void*{ void* p = ws + off; off += (bytes + 255) & ~(size_t)255; return p; };
  bf16_t* X2Q = (bf16_t*)alloc(16ull*4*4*68*68*8*2); // quad-split padded channels-last
  bf16_t* WCQ = (bf16_t*)alloc(737280ull*2);
  bf16_t* RCWQ= (bf16_t*)alloc(36864ull*2);
  bf16_t* LF  = (bf16_t*)alloc(16ull*4096*32*2);
  bf16_t* OUTP= (bf16_t*)alloc(16ull*128*4096*2);
  float* PC2  = (float*)alloc(2048*4);               // PC2+CSUM+CSSQ contiguous
  float* CSUM = (float*)alloc(2048*4);
  float* CSSQ = (float*)alloc(2048*4);
  float* P    = (float*)alloc(2048*4);
  float* GB   = (float*)alloc(2048*4);
  float* GATE = (float*)alloc(2048*4);
  float* GF   = (float*)alloc(512*4);
  float* SIN  = (float*)alloc(16ull*8192*4);
  float* SATT = (float*)alloc(16ull*4096*4);
  float* SCA  = (float*)alloc(2048*4);
  float* SHB  = (float*)alloc(2048*4);

  (void)hipMemsetAsync(PC2, 0, 3*8192, stream);  // PC2, CSUM, CSSQ

  k_wprep  <<<3024, 256, 0, stream>>>(base_w, delta_w, kscale, rc_w, WCQ, RCWQ);
  k_pool   <<<2048, 256, 0, stream>>>(x, P);
  k_small1 <<<16,   128, 0, stream>>>(P, gc_w1, gc_w2, cg_w1, cg_b1, cg_w2, cg_b2, GB, GATE);
  k_spatial<<<256,  256, 0, stream>>>(x, GB, SIN);
  k_sgconv <<<256,  256, 0, stream>>>(SIN, sg_w, SATT);
  k_zb     <<<256,  256, 0, stream>>>(X2Q);
  k_x2     <<<1024, 256, 0, stream>>>(x, GATE, SATT, X2Q, PC2);
  k_small2 <<<16,    64, 0, stream>>>(PC2, rg_w, GF);
  k_router <<<256,  256, 0, stream>>>(X2Q, RCWQ, bn_g, bn_b, bn_m, bn_v, GF, LF);
  k_main   <<<1024, 256, 0, stream>>>(X2Q, WCQ, LF, gate_w, gate_b, OUTP, CSUM, CSSQ);
  k_small3 <<<16,   128, 0, stream>>>(CSUM, CSSQ, gn_g, gn_b, se_w1, se_b1, se_w2, se_b2, SCA, SHB);
  k_final  <<<4096, 256, 0, stream>>>(OUTP, x, SCA, SHB, bias, iscale, out);
}

// Round 5
// 354.298 us; speedup vs baseline: 6.8550x; 1.0384x over previous
//
#include <hip/hip_runtime.h>
#include <hip/hip_bf16.h>
#include <math.h>

typedef __bf16 bf16_t;
typedef __bf16 bf16x8 __attribute__((ext_vector_type(8)));
typedef __bf16 bf16x4 __attribute__((ext_vector_type(4)));
typedef __bf16 bf16x2 __attribute__((ext_vector_type(2)));
typedef float  f32x4  __attribute__((ext_vector_type(4)));

#define EPSF 1e-5f
#define TAUF 1.5f

__device__ __forceinline__ float sigmoidf_(float x){ return 1.f/(1.f+__expf(-x)); }
__device__ __forceinline__ float siluf_(float x){ return x*sigmoidf_(x); }

__device__ __forceinline__ void gload_lds16(const void* g, void* l){
  __builtin_amdgcn_global_load_lds((const __attribute__((address_space(1))) unsigned int*)g,
                                   (__attribute__((address_space(3))) unsigned int*)l, 16, 0, 0);
}

// ---------------- p[b,c] = mean_hw(x) ----------------
__global__ void k_pool(const float* __restrict__ x, float* __restrict__ p){
  int bc = blockIdx.x; const float* xr = x + (size_t)bc*4096;
  float s = 0.f;
  for (int i = threadIdx.x; i < 4096; i += 256) s += xr[i];
  __shared__ float sb[4];
  for (int off=32; off; off>>=1) s += __shfl_down(s, off);
  if ((threadIdx.x & 63)==0) sb[threadIdx.x>>6] = s;
  __syncthreads();
  if (threadIdx.x==0) p[bc] = (sb[0]+sb[1]+sb[2]+sb[3]) * (1.f/4096.f);
}

// ---------------- per-b tiny MLPs ----------------
__global__ void k_small1(const float* __restrict__ p, const float* __restrict__ gc_w1,
                         const float* __restrict__ gc_w2, const float* __restrict__ cg_w1,
                         const float* __restrict__ cg_b1, const float* __restrict__ cg_w2,
                         const float* __restrict__ cg_b2,
                         float* __restrict__ gbuf, float* __restrict__ gate){
  int b = blockIdx.x; int t = threadIdx.x; // 128 threads
  __shared__ float ps[128], h1[32], pc[128], c1[16];
  ps[t] = p[b*128+t];
  __syncthreads();
  if (t < 32){ float a=0.f; for(int c=0;c<128;c++) a += ps[c]*gc_w1[t*128+c]; h1[t]=siluf_(a); }
  __syncthreads();
  float a=0.f; for(int j=0;j<32;j++) a += h1[j]*gc_w2[t*32+j];
  float g = sigmoidf_(a);
  gbuf[b*128+t] = g; pc[t] = ps[t]*g;   // mean(x*g) = g*mean(x)
  __syncthreads();
  if (t < 16){ float a2=cg_b1[t]; for(int c=0;c<128;c++) a2 += pc[c]*cg_w1[t*128+c]; c1[t]=siluf_(a2); }
  __syncthreads();
  float a3=cg_b2[t]; for(int j=0;j<16;j++) a3 += c1[j]*cg_w2[t*16+j];
  gate[b*128+t] = g * sigmoidf_(a3);
}

// ---------------- s_in: mean/max over channels of x*g ----------------
__global__ void k_spatial(const float* __restrict__ x, const float* __restrict__ gbuf,
                          float* __restrict__ sin_){
  int bi = blockIdx.x; int b = bi>>4; int h = ((bi&15)<<2) + (threadIdx.x>>6); int w = threadIdx.x&63;
  float sm=0.f, mx=-1e30f;
  for (int c=0;c<128;c++){
    float v = x[(((size_t)(b*128+c))*64 + h)*64 + w] * gbuf[b*128+c];
    sm += v; mx = fmaxf(mx, v);
  }
  sin_[b*8192 + h*64 + w]        = sm*(1.f/128.f);
  sin_[b*8192 + 4096 + h*64 + w] = mx;
}

// ---------------- 7x7 spatial-gate conv ----------------
__global__ void k_sgconv(const float* __restrict__ sin_, const float* __restrict__ sg_w,
                         float* __restrict__ satt){
  int bi = blockIdx.x; int b = bi>>4; int h = ((bi&15)<<2)+(threadIdx.x>>6); int w = threadIdx.x&63;
  float a = 0.f;
  for (int c2=0;c2<2;c2++){
    const float* sp = sin_ + b*8192 + c2*4096;
    const float* wp = sg_w + c2*49;
    for (int di=0;di<7;di++){ int hh=h+di-3; if (hh<0||hh>=64) continue;
      for (int dj=0;dj<7;dj++){ int ww=w+dj-3; if (ww<0||ww>=64) continue;
        a += sp[hh*64+ww]*wp[di*7+dj]; } }
  }
  satt[b*4096 + h*64 + w] = sigmoidf_(a);
}

// ---------------- zero X2Q borders (2-halo, 256 planes of [68][68][8]) ----------------
__global__ void k_zb(bf16_t* __restrict__ x2q){
  size_t base = (size_t)blockIdx.x*68*68*8;
  float4 z = {0.f,0.f,0.f,0.f};
  for (int i = threadIdx.x; i < 272; i += 256){
    int r = i/68; int wp = i - r*68;
    int hp = (r&1) + (r>>1)*66;
    *(float4*)(x2q + base + ((size_t)hp*68 + wp)*8) = z;
  }
  {
    int i = threadIdx.x;
    int hp = 2 + (i>>2);
    int wp = (i&1) + (i&2)*33;
    *(float4*)(x2q + base + ((size_t)hp*68 + wp)*8) = z;
  }
}

// ---------------- x2 -> quad-split channels-last padded bf16 ----------------
// X2Q layout: [b][h2(4)][q(4)][68][68][8ch], original (h,w) at padded (h+2, w+2)
__global__ void k_x2(const float* __restrict__ x, const float* __restrict__ gate,
                     const float* __restrict__ satt, bf16_t* __restrict__ x2q,
                     float* __restrict__ pc2){
  int bi = blockIdx.x; int b = bi>>6; int h = bi&63;
  __shared__ bf16_t tile[128*66];
  int wv = threadIdx.x>>6, lane = threadIdx.x&63;
  float sa = satt[b*4096 + h*64 + lane];
  for (int it=0; it<32; it++){
    int c = it*4 + wv;
    float v = x[(((size_t)(b*128+c))*64 + h)*64 + lane] * gate[b*128+c] * sa;
    tile[c*66 + lane] = (bf16_t)v;
    float s = v;
    for (int off=32; off; off>>=1) s += __shfl_down(s, off);
    if (lane==0) atomicAdd(&pc2[b*128+c], s);
  }
  __syncthreads();
  for (int it=0; it<4; it++){
    int idx = it*256 + threadIdx.x;
    int cq = idx>>6; int w = idx&63;
    int c0 = cq*8;
    bf16x8 v;
    #pragma unroll
    for (int e=0;e<8;e++) v[e] = tile[(c0+e)*66 + w];
    *(bf16x8*)(x2q + (((((size_t)b*4 + (cq>>2))*4 + (cq&3))*68 + (h+2))*68 + (w+2))*8) = v;
  }
}

// ---------------- gf = silu(mean(x2) @ rg_w^T) ----------------
__global__ void k_small2(const float* __restrict__ pc2, const float* __restrict__ rg_w,
                         float* __restrict__ gf){
  int b = blockIdx.x; int t = threadIdx.x;
  if (t < 32){
    float a=0.f; for(int c=0;c<128;c++) a += pc2[b*128+c]*(1.f/4096.f)*rg_w[t*128+c];
    gf[b*32+t] = siluf_(a);
  }
}

// ---------------- weight prep ----------------
// WCQ [ob(8)][t(9)][h2(4)][s(4)][q(4)][o16(16)][c8(8)] bf16, W'_s = base + delta_s*scale
// RCWQ [h2(4)][t(9)][n2(2)][q(4)][h16(16)][c8(8)] bf16
__global__ void k_wprep(const float* __restrict__ base_w, const float* __restrict__ delta_w,
                        const float* __restrict__ kscale, const float* __restrict__ rc_w,
                        bf16_t* __restrict__ WCQ, bf16_t* __restrict__ RCWQ){
  int i = blockIdx.x*256 + threadIdx.x;
  if (i < 589824){
    int c8 = i&7; int o16 = (i>>3)&15; int q = (i>>7)&3; int s = (i>>9)&3;
    int h2 = (i>>11)&3; int r = i>>13; int t = r%9; int ob = r/9;
    int o = ob*16 + o16; int c = h2*32 + q*8 + c8;
    float v = base_w[(o*128+c)*9 + t] + delta_w[(((s*128)+o)*128 + c)*9 + t]*kscale[s*128+o];
    WCQ[i] = (bf16_t)v;
  } else if (i < 589824 + 36864){
    int j = i - 589824;
    int c8 = j&7; int h16 = (j>>3)&15; int q = (j>>7)&3; int n2 = (j>>9)&1;
    int r = j>>10; int t = r%9; int h2 = r/9;
    int hid = n2*16 + h16; int c = h2*32 + q*8 + c8;
    RCWQ[j] = (bf16_t)rc_w[(hid*128+c)*9 + t];
  }
}

// ---------------- router: strip + all-taps-resident MFMA ----------------
// grid 512 = b(16) x rb(32 strips of 2 rows). M=128 pos, N=32 hid, K=1152.
// Per h2: stage 6-row strip (4 q-planes) + all 9 taps' weights, then 36 MFMA/wave.
__global__ void __launch_bounds__(256) k_router(
    const bf16_t* __restrict__ x2q, const bf16_t* __restrict__ RCWQ,
    const float* __restrict__ bn_gamma, const float* __restrict__ bn_beta,
    const float* __restrict__ bn_mean, const float* __restrict__ bn_var,
    const float* __restrict__ gf, bf16_t* __restrict__ lfb){
  __shared__ __align__(16) char smem[44544]; // strip 4x6528=26112 + weights 18432
  int tid = threadIdx.x;
  int wv = tid>>6, lane = tid&63, m16 = lane&15, q = lane>>4;
  int rb = blockIdx.x & 31, b = blockIdx.x >> 5;
  int r0 = rb*2;
  int rloc = wv&1;
  int ws0 = (wv>>1)*2;

  f32x4 acc[2][2] = {};   // [n2][mt]

  #pragma unroll 1
  for (int h2=0; h2<4; h2++){
    // strip: wave wv stages q-plane wv, padded rows r0..r0+5 (6528 B)
    const char* asrc = (const char*)(x2q + ((((size_t)(b*4+h2)*4 + wv)*68 + r0)*68)*8);
    #pragma unroll
    for (int j=0;j<7;j++){
      if (j*64 + lane < 408)
        gload_lds16(asrc + j*1024 + lane*16, (char*)smem + wv*6528 + j*1024);
    }
    // weights for this h2: 18432 B, wave wv stages quarter wv (4608 B)
    const char* wsrc = (const char*)(RCWQ + (size_t)h2*9216) + wv*4608;
    #pragma unroll
    for (int j=0;j<5;j++){
      if (j*64 + lane < 288)
        gload_lds16(wsrc + j*1024 + lane*16, (char*)smem + 26112 + wv*4608 + j*1024);
    }
    __syncthreads();
    #pragma unroll 1
    for (int t=0; t<9; t++){
      int di = t/3, dj = t - di*3;
      bf16x8 aw0 = *(const bf16x8*)((const char*)smem + 26112 + (t*2+0)*1024 + q*256 + m16*16);
      bf16x8 aw1 = *(const bf16x8*)((const char*)smem + 26112 + (t*2+1)*1024 + q*256 + m16*16);
      #pragma unroll
      for (int mt=0; mt<2; mt++){
        int wseg = ws0 + mt;
        bf16x8 bs = *(const bf16x8*)((const char*)smem + q*6528 +
                     ((rloc + 2*di)*68 + wseg*16 + m16 + 2*dj)*16);
        acc[0][mt] = __builtin_amdgcn_mfma_f32_16x16x32_bf16(aw0, bs, acc[0][mt], 0,0,0);
        acc[1][mt] = __builtin_amdgcn_mfma_f32_16x16x32_bf16(aw1, bs, acc[1][mt], 0,0,0);
      }
    }
    __syncthreads();
  }

  // epilogue: BN + silu + gf, bf16 channels-last
  #pragma unroll
  for (int n2=0;n2<2;n2++){
    float aa[4], bb[4];
    #pragma unroll
    for (int i=0;i<4;i++){
      int hid = n2*16 + q*4 + i;
      float a = bn_gamma[hid]*rsqrtf(bn_var[hid]+EPSF);
      aa[i] = a;
      bb[i] = bn_beta[hid] - bn_mean[hid]*a;
    }
    #pragma unroll
    for (int mt=0;mt<2;mt++){
      bf16x4 yv;
      #pragma unroll
      for (int i=0;i<4;i++){
        int hid = n2*16 + q*4 + i;
        yv[i] = (bf16_t)(siluf_(aa[i]*acc[n2][mt][i] + bb[i]) + gf[b*32+hid]);
      }
      size_t pos = (size_t)b*4096 + (r0+rloc)*64 + (ws0+mt)*16 + m16;
      *(bf16x4*)(lfb + pos*32 + n2*16 + q*4) = yv;
    }
  }
}

// ---------------- main dynamic conv: strip-resident implicit GEMM, base folded ----------------
// grid: 1024 = b(16) x hb(8 rows of 8) x ob(8 o-tiles of 16)
// M=512 (8 rows x 64 w), N=64 (4 segs x 16 o), K=1152
__global__ void __launch_bounds__(256, 2) k_main(
    const bf16_t* __restrict__ x2q, const bf16_t* __restrict__ WCQ,
    const bf16_t* __restrict__ lfb, const float* __restrict__ gate_w,
    const float* __restrict__ gate_b, bf16_t* __restrict__ outp,
    float* __restrict__ csum, float* __restrict__ cssq){
  __shared__ __align__(16) char smem[52288];
  // strip: 4 q-planes x 10896B (10880 data + 16 pad) = 43584; B dbuf 2x4096 @43584; sred @51776
  bf16_t* shGW  = (bf16_t*)(smem + 43584);  // epi: [64][32] = 4096 B
  float*  sred  = (float*)(smem + 51776);

  int tid = threadIdx.x;
  int wv = tid>>6, lane = tid&63, m16 = lane&15, q = lane>>4;
  int bx = blockIdx.x;
  int ob = bx & 7, hb = (bx>>3) & 7, b = bx>>6;
  int h0 = hb*8, obase = ob*16;

  f32x4 acc[8][4] = {};

  int baseA[8];
  #pragma unroll
  for (int mi=0;mi<8;mi++){
    int row = wv*2 + (mi>>2); int wseg = mi&3;
    baseA[mi] = (row*68 + wseg*16 + m16 + 1)*16 + q*10896;
  }
  int baseB = q*256 + m16*16;

  #pragma unroll 1
  for (int h2=0; h2<4; h2++){
    // stage strip: wave wv stages q-plane wv, padded rows h0+1..h0+10 (10880 B)
    const char* asrc = (const char*)(x2q + ((((size_t)(b*4+h2)*4 + wv)*68 + (h0+1))*68)*8);
    #pragma unroll
    for (int j=0;j<11;j++){
      if (j*64 + lane < 680)
        gload_lds16(asrc + j*1024 + lane*16, (char*)smem + wv*10896 + j*1024);
    }
    // stage B(t=0): 4096 B, wave wv stages s-block wv
    {
      const char* bsrc = (const char*)(WCQ + ((size_t)((ob*9 + 0)*4 + h2))*2048);
      gload_lds16(bsrc + wv*1024 + lane*16, (char*)smem + 43584 + wv*1024);
    }
    __syncthreads();
    #pragma unroll 1
    for (int t=0; t<9; t++){
      const char* Bcur = smem + 43584 + (t&1)*4096;
      if (t < 8){
        const char* bsrc = (const char*)(WCQ + ((size_t)((ob*9 + t+1)*4 + h2))*2048);
        gload_lds16(bsrc + wv*1024 + lane*16,
                    (char*)smem + 43584 + ((t+1)&1)*4096 + wv*1024);
      }
      int di = t/3, dj = t - di*3;
      int toff = (di*68 + dj)*16;
      bf16x8 av[8], bv[4];
      #pragma unroll
      for (int mi=0;mi<8;mi++) av[mi] = *(const bf16x8*)((const char*)smem + baseA[mi] + toff);
      #pragma unroll
      for (int s=0;s<4;s++)  bv[s] = *(const bf16x8*)(Bcur + s*1024 + baseB);
      #pragma unroll
      for (int s=0;s<4;s++){
        #pragma unroll
        for (int mi=0;mi<8;mi++)
          acc[mi][s] = __builtin_amdgcn_mfma_f32_16x16x32_bf16(av[mi], bv[s], acc[mi][s], 0,0,0);
      }
      __syncthreads();
    }
  }

  // ---- epilogue: gate logits + softmax + combine + GN-stats ----
  const char* lfsrc = (const char*)(lfb + ((size_t)b*4096 + h0*64)*32);
  for (int i = wv; i < 32; i += 4)
    gload_lds16(lfsrc + i*1024 + lane*16, (char*)smem + i*1024);
  for (int idx = tid; idx < 2048; idx += 256){
    int n = idx>>5, j = idx&31;
    shGW[n*32+j] = (bf16_t)gate_w[((n>>4)*128 + obase + (n&15))*32 + j];
  }
  __syncthreads();

  bf16x8 bg[4];
  #pragma unroll
  for (int kk=0;kk<4;kk++) bg[kk] = *(const bf16x8*)((const char*)shGW + (kk*16+m16)*64 + q*16);
  float gb[4];
  #pragma unroll
  for (int kk=0;kk<4;kk++) gb[kk] = gate_b[kk*128 + obase + m16];

  const float itau = 1.f/TAUF;
  float s1 = 0.f, s2 = 0.f;
  size_t orow = ((size_t)(b*128 + obase + m16))*4096 + h0*64;
  #pragma unroll
  for (int mi=0; mi<8; mi++){
    bf16x8 avL = *(const bf16x8*)((const char*)smem + (wv*128 + mi*16 + m16)*64 + q*16);
    f32x4 zero = {};
    f32x4 lg[4];
    #pragma unroll
    for (int kk=0;kk<4;kk++)
      lg[kk] = __builtin_amdgcn_mfma_f32_16x16x32_bf16(avL, bg[kk], zero, 0,0,0);
    bf16x4 yv;
    #pragma unroll
    for (int r=0;r<4;r++){
      float l0 = (lg[0][r]+gb[0])*itau, l1 = (lg[1][r]+gb[1])*itau;
      float l2 = (lg[2][r]+gb[2])*itau, l3 = (lg[3][r]+gb[3])*itau;
      float mx = fmaxf(fmaxf(l0,l1),fmaxf(l2,l3));
      float e0=__expf(l0-mx), e1=__expf(l1-mx), e2=__expf(l2-mx), e3=__expf(l3-mx);
      float inv = 1.f/(e0+e1+e2+e3);
      float y = (e0*acc[mi][0][r] + e1*acc[mi][1][r]
               + e2*acc[mi][2][r] + e3*acc[mi][3][r])*inv;
      s1 += y; s2 += y*y;
      yv[r] = (bf16_t)y;
    }
    *(bf16x4*)(outp + orow + wv*128 + mi*16 + q*4) = yv;
  }

  s1 += __shfl_down(s1, 32); s1 += __shfl_down(s1, 16);
  s2 += __shfl_down(s2, 32); s2 += __shfl_down(s2, 16);
  if (lane < 16){ sred[wv*16 + lane] = s1; sred[64 + wv*16 + lane] = s2; }
  __syncthreads();
  if (tid < 16){
    float a = sred[tid] + sred[16+tid] + sred[32+tid] + sred[48+tid];
    float c = sred[64+tid] + sred[80+tid] + sred[96+tid] + sred[112+tid];
    atomicAdd(&csum[b*128 + obase + tid], a);
    atomicAdd(&cssq[b*128 + obase + tid], c);
  }
}

// ---------------- GroupNorm stats + output-SE -> per-(b,o) affine ----------------
__global__ void k_small3(const float* __restrict__ csum, const float* __restrict__ cssq,
                         const float* __restrict__ gn_gamma, const float* __restrict__ gn_beta,
                         const float* __restrict__ se_w1, const float* __restrict__ se_b1,
                         const float* __restrict__ se_w2, const float* __restrict__ se_b2,
                         float* __restrict__ sca, float* __restrict__ shb){
  int b = blockIdx.x; int o = threadIdx.x; // 128
  __shared__ float s1[128], s2[128], gmu[8], grs[8], psl[128], t1[16];
  s1[o] = csum[b*128+o]; s2[o] = cssq[b*128+o];
  __syncthreads();
  if (o<8){
    float a=0.f,a2=0.f; for(int j=0;j<16;j++){ a+=s1[o*16+j]; a2+=s2[o*16+j]; }
    float mu = a*(1.f/65536.f); float var = a2*(1.f/65536.f) - mu*mu;
    gmu[o]=mu; grs[o]=rsqrtf(var+EPSF);
  }
  __syncthreads();
  int g = o>>4;
  psl[o] = (s1[o]*(1.f/4096.f) - gmu[g])*grs[g]*gn_gamma[o] + gn_beta[o];
  __syncthreads();
  if (o<16){ float a = se_b1[o]; for(int c=0;c<128;c++) a += psl[c]*se_w1[o*128+c]; t1[o]=siluf_(a); }
  __syncthreads();
  float a = se_b2[o]; for(int j=0;j<16;j++) a += t1[j]*se_w2[o*16+j];
  float sev = sigmoidf_(a);
  sca[b*128+o] = grs[g]*gn_gamma[o]*sev;
  shb[b*128+o] = (gn_beta[o] - gmu[g]*grs[g]*gn_gamma[o])*sev;
}

// ---------------- final ----------------
__global__ void k_final(const bf16_t* __restrict__ outp, const float* __restrict__ x,
                        const float* __restrict__ sca, const float* __restrict__ shb,
                        const float* __restrict__ bias, const float* __restrict__ iscale,
                        float* __restrict__ out){
  float ts = tanhf(iscale[0]);
  size_t i = ((size_t)blockIdx.x*256 + threadIdx.x)*8;
  int bo = (int)(i>>12); int o = bo&127;
  float A = sca[bo], Bv = shb[bo] + bias[o];
  bf16x8 ov = *(const bf16x8*)(outp + i);
  float4 x0 = *(const float4*)(x+i), x1 = *(const float4*)(x+i+4);
  float4 r0, r1;
  r0.x = (float)ov[0]*A + Bv + ts*x0.x;
  r0.y = (float)ov[1]*A + Bv + ts*x0.y;
  r0.z = (float)ov[2]*A + Bv + ts*x0.z;
  r0.w = (float)ov[3]*A + Bv + ts*x0.w;
  r1.x = (float)ov[4]*A + Bv + ts*x1.x;
  r1.y = (float)ov[5]*A + Bv + ts*x1.y;
  r1.z = (float)ov[6]*A + Bv + ts*x1.z;
  r1.w = (float)ov[7]*A + Bv + ts*x1.w;
  *(float4*)(out+i) = r0; *(float4*)(out+i+4) = r1;
}

extern "C" void kernel_launch(void* const* d_in, const int* in_sizes, int n_in,
                              void* d_out, int out_size, void* d_ws, size_t ws_size,
                              hipStream_t stream){
  const float* x      = (const float*)d_in[0];
  const float* base_w = (const float*)d_in[1];
  const float* delta_w= (const float*)d_in[2];
  const float* kscale = (const float*)d_in[3];
  const float* gc_w1  = (const float*)d_in[4];
  const float* gc_w2  = (const float*)d_in[5];
  const float* rc_w   = (const float*)d_in[6];
  const float* bn_g   = (const float*)d_in[7];
  const float* bn_b   = (const float*)d_in[8];
  const float* bn_m   = (const float*)d_in[9];
  const float* bn_v   = (const float*)d_in[10];
  const float* rg_w   = (const float*)d_in[11];
  const float* gate_w = (const float*)d_in[12];
  const float* gate_b = (const float*)d_in[13];
  const float* cg_w1  = (const float*)d_in[14];
  const float* cg_b1  = (const float*)d_in[15];
  const float* cg_w2  = (const float*)d_in[16];
  const float* cg_b2  = (const float*)d_in[17];
  const float* sg_w   = (const float*)d_in[18];
  const float* gn_g   = (const float*)d_in[19];
  const float* gn_b   = (const float*)d_in[20];
  const float* se_w1  = (const float*)d_in[21];
  const float* se_b1  = (const float*)d_in[22];
  const float* se_w2  = (const float*)d_in[23];
  const float* se_b2  = (const float*)d_in[24];
  const float* iscale = (const float*)d_in[25];
  const float* bias   = (const float*)d_in[26];
  float* out = (float*)d_out;

  char* ws = (char*)d_ws;
  size_t off = 0;
  auto alloc = [&](size_t bytes)->void*{ void* p = ws + off; off += (bytes + 255) & ~(size_t)255; return p; };
  bf16_t* X2Q = (bf16_t*)alloc(16ull*4*4*68*68*8*2); // quad-split padded channels-last
  bf16_t* WCQ = (bf16_t*)alloc(589824ull*2);
  bf16_t* RCWQ= (bf16_t*)alloc(36864ull*2);
  bf16_t* LF  = (bf16_t*)alloc(16ull*4096*32*2);
  bf16_t* OUTP= (bf16_t*)alloc(16ull*128*4096*2);
  float* PC2  = (float*)alloc(2048*4);               // PC2+CSUM+CSSQ contiguous
  float* CSUM = (float*)alloc(2048*4);
  float* CSSQ = (float*)alloc(2048*4);
  float* P    = (float*)alloc(2048*4);
  float* GB   = (float*)alloc(2048*4);
  float* GATE = (float*)alloc(2048*4);
  float* GF   = (float*)alloc(512*4);
  float* SIN  = (float*)alloc(16ull*8192*4);
  float* SATT = (float*)alloc(16ull*4096*4);
  float* SCA  = (float*)alloc(2048*4);
  float* SHB  = (float*)alloc(2048*4);

  (void)hipMemsetAsync(PC2, 0, 3*8192, stream);  // PC2, CSUM, CSSQ

  k_wprep  <<<2448, 256, 0, stream>>>(base_w, delta_w, kscale, rc_w, WCQ, RCWQ);
  k_pool   <<<2048, 256, 0, stream>>>(x, P);
  k_small1 <<<16,   128, 0, stream>>>(P, gc_w1, gc_w2, cg_w1, cg_b1, cg_w2, cg_b2, GB, GATE);
  k_spatial<<<256,  256, 0, stream>>>(x, GB, SIN);
  k_sgconv <<<256,  256, 0, stream>>>(SIN, sg_w, SATT);
  k_zb     <<<256,  256, 0, stream>>>(X2Q);
  k_x2     <<<1024, 256, 0, stream>>>(x, GATE, SATT, X2Q, PC2);
  k_small2 <<<16,    64, 0, stream>>>(PC2, rg_w, GF);
  k_router <<<512,  256, 0, stream>>>(X2Q, RCWQ, bn_g, bn_b, bn_m, bn_v, GF, LF);
  k_main   <<<1024, 256, 0, stream>>>(X2Q, WCQ, LF, gate_w, gate_b, OUTP, CSUM, CSSQ);
  k_small3 <<<16,   128, 0, stream>>>(CSUM, CSSQ, gn_g, gn_b, se_w1, se_b1, se_w2, se_b2, SCA, SHB);
  k_final  <<<4096, 256, 0, stream>>>(OUTP, x, SCA, SHB, bias, iscale, out);
}

// Round 6
// 321.235 us; speedup vs baseline: 7.5605x; 1.1029x over previous
//
#include <hip/hip_runtime.h>
#include <hip/hip_bf16.h>
#include <math.h>

typedef __bf16 bf16_t;
typedef __bf16 bf16x8 __attribute__((ext_vector_type(8)));
typedef __bf16 bf16x4 __attribute__((ext_vector_type(4)));
typedef __bf16 bf16x2 __attribute__((ext_vector_type(2)));
typedef float  f32x4  __attribute__((ext_vector_type(4)));

#define EPSF 1e-5f
#define TAUF 1.5f

__device__ __forceinline__ float sigmoidf_(float x){ return 1.f/(1.f+__expf(-x)); }
__device__ __forceinline__ float siluf_(float x){ return x*sigmoidf_(x); }

__device__ __forceinline__ void gload_lds16(const void* g, void* l){
  __builtin_amdgcn_global_load_lds((const __attribute__((address_space(1))) unsigned int*)g,
                                   (__attribute__((address_space(3))) unsigned int*)l, 16, 0, 0);
}

// ---------------- p[b,c] = mean_hw(x) ----------------
__global__ void k_pool(const float* __restrict__ x, float* __restrict__ p){
  int bc = blockIdx.x; const float* xr = x + (size_t)bc*4096;
  float s = 0.f;
  for (int i = threadIdx.x; i < 4096; i += 256) s += xr[i];
  __shared__ float sb[4];
  for (int off=32; off; off>>=1) s += __shfl_down(s, off);
  if ((threadIdx.x & 63)==0) sb[threadIdx.x>>6] = s;
  __syncthreads();
  if (threadIdx.x==0) p[bc] = (sb[0]+sb[1]+sb[2]+sb[3]) * (1.f/4096.f);
}

// ---------------- per-b tiny MLPs ----------------
__global__ void k_small1(const float* __restrict__ p, const float* __restrict__ gc_w1,
                         const float* __restrict__ gc_w2, const float* __restrict__ cg_w1,
                         const float* __restrict__ cg_b1, const float* __restrict__ cg_w2,
                         const float* __restrict__ cg_b2,
                         float* __restrict__ gbuf, float* __restrict__ gate){
  int b = blockIdx.x; int t = threadIdx.x; // 128 threads
  __shared__ float ps[128], h1[32], pc[128], c1[16];
  ps[t] = p[b*128+t];
  __syncthreads();
  if (t < 32){ float a=0.f; for(int c=0;c<128;c++) a += ps[c]*gc_w1[t*128+c]; h1[t]=siluf_(a); }
  __syncthreads();
  float a=0.f; for(int j=0;j<32;j++) a += h1[j]*gc_w2[t*32+j];
  float g = sigmoidf_(a);
  gbuf[b*128+t] = g; pc[t] = ps[t]*g;   // mean(x*g) = g*mean(x)
  __syncthreads();
  if (t < 16){ float a2=cg_b1[t]; for(int c=0;c<128;c++) a2 += pc[c]*cg_w1[t*128+c]; c1[t]=siluf_(a2); }
  __syncthreads();
  float a3=cg_b2[t]; for(int j=0;j<16;j++) a3 += c1[j]*cg_w2[t*16+j];
  gate[b*128+t] = g * sigmoidf_(a3);
}

// ---------------- s_in: mean/max over channels of x*g (1 row / block) ----------------
__global__ void k_spatial(const float* __restrict__ x, const float* __restrict__ gbuf,
                          float* __restrict__ sin_){
  int bi = blockIdx.x; int b = bi>>6; int h = bi&63;
  int wv = threadIdx.x>>6, w = threadIdx.x&63;
  __shared__ float psum[4][64], pmax[4][64];
  float sm=0.f, mx=-1e30f;
  const float* xb = x + (((size_t)b*128 + wv*32)*64 + h)*64 + w;
  const float* gb = gbuf + b*128 + wv*32;
  #pragma unroll 4
  for (int c=0;c<32;c++){
    float v = xb[(size_t)c*4096] * gb[c];
    sm += v; mx = fmaxf(mx, v);
  }
  psum[wv][w]=sm; pmax[wv][w]=mx;
  __syncthreads();
  if (threadIdx.x < 64){
    float s = psum[0][w]+psum[1][w]+psum[2][w]+psum[3][w];
    float m = fmaxf(fmaxf(pmax[0][w],pmax[1][w]),fmaxf(pmax[2][w],pmax[3][w]));
    sin_[b*8192 + h*64 + w]        = s*(1.f/128.f);
    sin_[b*8192 + 4096 + h*64 + w] = m;
  }
}

// ---------------- zero X2Q borders (2-halo, 256 planes of [68][68][8]) ----------------
__global__ void k_zb(bf16_t* __restrict__ x2q){
  size_t base = (size_t)blockIdx.x*68*68*8;
  float4 z = {0.f,0.f,0.f,0.f};
  for (int i = threadIdx.x; i < 272; i += 256){
    int r = i/68; int wp = i - r*68;
    int hp = (r&1) + (r>>1)*66;
    *(float4*)(x2q + base + ((size_t)hp*68 + wp)*8) = z;
  }
  {
    int i = threadIdx.x;
    int hp = 2 + (i>>2);
    int wp = (i&1) + (i&2)*33;
    *(float4*)(x2q + base + ((size_t)hp*68 + wp)*8) = z;
  }
}

// ---------------- x2: fused 7x7 spatial-gate + gating + quad-split store ----------------
// X2Q layout: [b][h2(4)][q(4)][68][68][8ch], original (h,w) at padded (h+2, w+2)
__global__ void k_x2(const float* __restrict__ x, const float* __restrict__ gate,
                     const float* __restrict__ sin_, const float* __restrict__ sg_w,
                     bf16_t* __restrict__ x2q, float* __restrict__ pc2){
  int bi = blockIdx.x; int b = bi>>6; int h = bi&63;
  __shared__ bf16_t tile[128*66];
  __shared__ float sh_sin[980];   // [c2(2)][r(7)][col(70)]
  __shared__ float sh_sgw[98];
  __shared__ float satt_row[64];
  int tid = threadIdx.x, wv = tid>>6, lane = tid&63;
  // stage s_in neighborhood (zero-padded) + weights
  for (int i=tid;i<980;i+=256){
    int c2 = i/490; int rr = i - c2*490; int r = rr/70; int k = rr - r*70;
    int hh = h + r - 3; int ww = k - 3;
    float v = 0.f;
    if (hh>=0 && hh<64 && ww>=0 && ww<64) v = sin_[b*8192 + c2*4096 + hh*64 + ww];
    sh_sin[i] = v;
  }
  if (tid < 98) sh_sgw[tid] = sg_w[tid];
  __syncthreads();
  if (tid < 64){
    float a = 0.f;
    #pragma unroll
    for (int c2=0;c2<2;c2++)
      #pragma unroll
      for (int r=0;r<7;r++)
        #pragma unroll
        for (int j=0;j<7;j++)
          a += sh_sin[c2*490 + r*70 + tid + j] * sh_sgw[c2*49 + r*7 + j];
    satt_row[tid] = sigmoidf_(a);
  }
  __syncthreads();
  float sa = satt_row[lane];
  for (int it=0; it<32; it++){
    int c = it*4 + wv;
    float v = x[(((size_t)(b*128+c))*64 + h)*64 + lane] * gate[b*128+c] * sa;
    tile[c*66 + lane] = (bf16_t)v;
    float s = v;
    for (int off=32; off; off>>=1) s += __shfl_down(s, off);
    if (lane==0) atomicAdd(&pc2[b*128+c], s);
  }
  __syncthreads();
  for (int it=0; it<4; it++){
    int idx = it*256 + tid;
    int cq = idx>>6; int w = idx&63;
    int c0 = cq*8;
    bf16x8 v;
    #pragma unroll
    for (int e=0;e<8;e++) v[e] = tile[(c0+e)*66 + w];
    *(bf16x8*)(x2q + (((((size_t)b*4 + (cq>>2))*4 + (cq&3))*68 + (h+2))*68 + (w+2))*8) = v;
  }
}

// ---------------- gf = silu(mean(x2) @ rg_w^T) ----------------
__global__ void k_small2(const float* __restrict__ pc2, const float* __restrict__ rg_w,
                         float* __restrict__ gf){
  int b = blockIdx.x; int t = threadIdx.x;
  if (t < 32){
    float a=0.f; for(int c=0;c<128;c++) a += pc2[b*128+c]*(1.f/4096.f)*rg_w[t*128+c];
    gf[b*32+t] = siluf_(a);
  }
}

// ---------------- weight prep ----------------
// WCQ [ob(8)][t(9)][h2(4)][s(4)][q(4)][o16(16)][c8(8)] bf16, W'_s = base + delta_s*scale
// RCWQ [h2(4)][t(9)][n2(2)][q(4)][h16(16)][c8(8)] bf16
__global__ void k_wprep(const float* __restrict__ base_w, const float* __restrict__ delta_w,
                        const float* __restrict__ kscale, const float* __restrict__ rc_w,
                        bf16_t* __restrict__ WCQ, bf16_t* __restrict__ RCWQ){
  int i = blockIdx.x*256 + threadIdx.x;
  if (i < 589824){
    int c8 = i&7; int o16 = (i>>3)&15; int q = (i>>7)&3; int s = (i>>9)&3;
    int h2 = (i>>11)&3; int r = i>>13; int t = r%9; int ob = r/9;
    int o = ob*16 + o16; int c = h2*32 + q*8 + c8;
    float v = base_w[(o*128+c)*9 + t] + delta_w[(((s*128)+o)*128 + c)*9 + t]*kscale[s*128+o];
    WCQ[i] = (bf16_t)v;
  } else if (i < 589824 + 36864){
    int j = i - 589824;
    int c8 = j&7; int h16 = (j>>3)&15; int q = (j>>7)&3; int n2 = (j>>9)&1;
    int r = j>>10; int t = r%9; int h2 = r/9;
    int hid = n2*16 + h16; int c = h2*32 + q*8 + c8;
    RCWQ[j] = (bf16_t)rc_w[(hid*128+c)*9 + t];
  }
}

// ---------------- router: strip + all-taps-resident MFMA ----------------
// grid 512 = b(16) x rb(32 strips of 2 rows). M=128 pos, N=32 hid, K=1152.
__global__ void __launch_bounds__(256) k_router(
    const bf16_t* __restrict__ x2q, const bf16_t* __restrict__ RCWQ,
    const float* __restrict__ bn_gamma, const float* __restrict__ bn_beta,
    const float* __restrict__ bn_mean, const float* __restrict__ bn_var,
    const float* __restrict__ gf, bf16_t* __restrict__ lfb){
  __shared__ __align__(16) char smem[44544]; // strip 4x6528=26112 + weights 18432
  int tid = threadIdx.x;
  int wv = tid>>6, lane = tid&63, m16 = lane&15, q = lane>>4;
  int rb = blockIdx.x & 31, b = blockIdx.x >> 5;
  int r0 = rb*2;
  int rloc = wv&1;
  int ws0 = (wv>>1)*2;

  f32x4 acc[2][2] = {};   // [n2][mt]

  #pragma unroll 1
  for (int h2=0; h2<4; h2++){
    const char* asrc = (const char*)(x2q + ((((size_t)(b*4+h2)*4 + wv)*68 + r0)*68)*8);
    #pragma unroll
    for (int j=0;j<7;j++){
      if (j*64 + lane < 408)
        gload_lds16(asrc + j*1024 + lane*16, (char*)smem + wv*6528 + j*1024);
    }
    const char* wsrc = (const char*)(RCWQ + (size_t)h2*9216) + wv*4608;
    #pragma unroll
    for (int j=0;j<5;j++){
      if (j*64 + lane < 288)
        gload_lds16(wsrc + j*1024 + lane*16, (char*)smem + 26112 + wv*4608 + j*1024);
    }
    __syncthreads();
    #pragma unroll
    for (int t=0; t<9; t++){
      int di = t/3, dj = t - di*3;
      bf16x8 aw0 = *(const bf16x8*)((const char*)smem + 26112 + (t*2+0)*1024 + q*256 + m16*16);
      bf16x8 aw1 = *(const bf16x8*)((const char*)smem + 26112 + (t*2+1)*1024 + q*256 + m16*16);
      #pragma unroll
      for (int mt=0; mt<2; mt++){
        int wseg = ws0 + mt;
        bf16x8 bs = *(const bf16x8*)((const char*)smem + q*6528 +
                     ((rloc + 2*di)*68 + wseg*16 + m16 + 2*dj)*16);
        acc[0][mt] = __builtin_amdgcn_mfma_f32_16x16x32_bf16(aw0, bs, acc[0][mt], 0,0,0);
        acc[1][mt] = __builtin_amdgcn_mfma_f32_16x16x32_bf16(aw1, bs, acc[1][mt], 0,0,0);
      }
    }
    __syncthreads();
  }

  #pragma unroll
  for (int n2=0;n2<2;n2++){
    float aa[4], bb[4];
    #pragma unroll
    for (int i=0;i<4;i++){
      int hid = n2*16 + q*4 + i;
      float a = bn_gamma[hid]*rsqrtf(bn_var[hid]+EPSF);
      aa[i] = a;
      bb[i] = bn_beta[hid] - bn_mean[hid]*a;
    }
    #pragma unroll
    for (int mt=0;mt<2;mt++){
      bf16x4 yv;
      #pragma unroll
      for (int i=0;i<4;i++){
        int hid = n2*16 + q*4 + i;
        yv[i] = (bf16_t)(siluf_(aa[i]*acc[n2][mt][i] + bb[i]) + gf[b*32+hid]);
      }
      size_t pos = (size_t)b*4096 + (r0+rloc)*64 + (ws0+mt)*16 + m16;
      *(bf16x4*)(lfb + pos*32 + n2*16 + q*4) = yv;
    }
  }
}

// ---------------- main dynamic conv: all-taps-resident implicit GEMM ----------------
// grid: 1024 = ob(8) x b(16) x hb(8)  [ob slowest -> same-strip blocks share XCD]
// M=512 (8 rows x 64 w), N=64 (4 segs x 16 o), K=1152. 8 barriers total.
__global__ void __launch_bounds__(256, 2) k_main(
    const bf16_t* __restrict__ x2q, const bf16_t* __restrict__ WCQ,
    const bf16_t* __restrict__ lfb, const float* __restrict__ gate_w,
    const float* __restrict__ gate_b, bf16_t* __restrict__ outp,
    float* __restrict__ csum, float* __restrict__ cssq){
  __shared__ __align__(16) char smem[80960];
  // strip: 4 q-planes x 10896B = 43584; B all-taps 9x4096=36864 @43584; sred @80448
  bf16_t* shGW  = (bf16_t*)(smem + 43584);  // epi: [64][32] = 4096 B
  float*  sred  = (float*)(smem + 80448);

  int tid = threadIdx.x;
  int wv = tid>>6, lane = tid&63, m16 = lane&15, q = lane>>4;
  int bx = blockIdx.x;
  int ob = bx >> 7; int rem = bx & 127; int b = rem >> 3; int hb = rem & 7;
  int h0 = hb*8, obase = ob*16;

  f32x4 acc[8][4] = {};

  int baseA[8];
  #pragma unroll
  for (int mi=0;mi<8;mi++){
    int row = wv*2 + (mi>>2); int wseg = mi&3;
    baseA[mi] = (row*68 + wseg*16 + m16 + 1)*16 + q*10896;
  }
  int baseB = q*256 + m16*16;

  #pragma unroll 1
  for (int h2=0; h2<4; h2++){
    // stage strip: wave wv stages q-plane wv, padded rows h0+1..h0+10 (10880 B)
    const char* asrc = (const char*)(x2q + ((((size_t)(b*4+h2)*4 + wv)*68 + (h0+1))*68)*8);
    #pragma unroll
    for (int j=0;j<11;j++){
      if (j*64 + lane < 680)
        gload_lds16(asrc + j*1024 + lane*16, (char*)smem + wv*10896 + j*1024);
    }
    // stage all 9 taps' B: 36864 B (each iter = one 4096B t-slice)
    const char* bsrc = (const char*)WCQ + ((size_t)(ob*9)*4 + h2)*4096;
    #pragma unroll
    for (int j=0;j<9;j++)
      gload_lds16(bsrc + j*16384 + wv*1024 + lane*16,
                  (char*)smem + 43584 + j*4096 + wv*1024);
    __syncthreads();
    #pragma unroll
    for (int t=0; t<9; t++){
      int di = t/3, dj = t - di*3;
      int toff = (di*68 + dj)*16;
      bf16x8 av[8], bv[4];
      #pragma unroll
      for (int mi=0;mi<8;mi++) av[mi] = *(const bf16x8*)((const char*)smem + baseA[mi] + toff);
      #pragma unroll
      for (int s=0;s<4;s++)  bv[s] = *(const bf16x8*)((const char*)smem + 43584 + t*4096 + s*1024 + baseB);
      #pragma unroll
      for (int s=0;s<4;s++){
        #pragma unroll
        for (int mi=0;mi<8;mi++)
          acc[mi][s] = __builtin_amdgcn_mfma_f32_16x16x32_bf16(av[mi], bv[s], acc[mi][s], 0,0,0);
      }
    }
    __syncthreads();
  }

  // ---- epilogue: gate logits + softmax + combine + GN-stats ----
  const char* lfsrc = (const char*)(lfb + ((size_t)b*4096 + h0*64)*32);
  for (int i = wv; i < 32; i += 4)
    gload_lds16(lfsrc + i*1024 + lane*16, (char*)smem + i*1024);
  for (int idx = tid; idx < 2048; idx += 256){
    int n = idx>>5, j = idx&31;
    shGW[n*32+j] = (bf16_t)gate_w[((n>>4)*128 + obase + (n&15))*32 + j];
  }
  __syncthreads();

  bf16x8 bg[4];
  #pragma unroll
  for (int kk=0;kk<4;kk++) bg[kk] = *(const bf16x8*)((const char*)shGW + (kk*16+m16)*64 + q*16);
  float gb[4];
  #pragma unroll
  for (int kk=0;kk<4;kk++) gb[kk] = gate_b[kk*128 + obase + m16];

  const float itau = 1.f/TAUF;
  float s1 = 0.f, s2 = 0.f;
  size_t orow = ((size_t)(b*128 + obase + m16))*4096 + h0*64;
  #pragma unroll
  for (int mi=0; mi<8; mi++){
    bf16x8 avL = *(const bf16x8*)((const char*)smem + (wv*128 + mi*16 + m16)*64 + q*16);
    f32x4 zero = {};
    f32x4 lg[4];
    #pragma unroll
    for (int kk=0;kk<4;kk++)
      lg[kk] = __builtin_amdgcn_mfma_f32_16x16x32_bf16(avL, bg[kk], zero, 0,0,0);
    bf16x4 yv;
    #pragma unroll
    for (int r=0;r<4;r++){
      float l0 = (lg[0][r]+gb[0])*itau, l1 = (lg[1][r]+gb[1])*itau;
      float l2 = (lg[2][r]+gb[2])*itau, l3 = (lg[3][r]+gb[3])*itau;
      float mx = fmaxf(fmaxf(l0,l1),fmaxf(l2,l3));
      float e0=__expf(l0-mx), e1=__expf(l1-mx), e2=__expf(l2-mx), e3=__expf(l3-mx);
      float inv = 1.f/(e0+e1+e2+e3);
      float y = (e0*acc[mi][0][r] + e1*acc[mi][1][r]
               + e2*acc[mi][2][r] + e3*acc[mi][3][r])*inv;
      s1 += y; s2 += y*y;
      yv[r] = (bf16_t)y;
    }
    *(bf16x4*)(outp + orow + wv*128 + mi*16 + q*4) = yv;
  }

  s1 += __shfl_down(s1, 32); s1 += __shfl_down(s1, 16);
  s2 += __shfl_down(s2, 32); s2 += __shfl_down(s2, 16);
  if (lane < 16){ sred[wv*16 + lane] = s1; sred[64 + wv*16 + lane] = s2; }
  __syncthreads();
  if (tid < 16){
    float a = sred[tid] + sred[16+tid] + sred[32+tid] + sred[48+tid];
    float c = sred[64+tid] + sred[80+tid] + sred[96+tid] + sred[112+tid];
    atomicAdd(&csum[b*128 + obase + tid], a);
    atomicAdd(&cssq[b*128 + obase + tid], c);
  }
}

// ---------------- GroupNorm stats + output-SE -> per-(b,o) affine ----------------
__global__ void k_small3(const float* __restrict__ csum, const float* __restrict__ cssq,
                         const float* __restrict__ gn_gamma, const float* __restrict__ gn_beta,
                         const float* __restrict__ se_w1, const float* __restrict__ se_b1,
                         const float* __restrict__ se_w2, const float* __restrict__ se_b2,
                         float* __restrict__ sca, float* __restrict__ shb){
  int b = blockIdx.x; int o = threadIdx.x; // 128
  __shared__ float s1[128], s2[128], gmu[8], grs[8], psl[128], t1[16];
  s1[o] = csum[b*128+o]; s2[o] = cssq[b*128+o];
  __syncthreads();
  if (o<8){
    float a=0.f,a2=0.f; for(int j=0;j<16;j++){ a+=s1[o*16+j]; a2+=s2[o*16+j]; }
    float mu = a*(1.f/65536.f); float var = a2*(1.f/65536.f) - mu*mu;
    gmu[o]=mu; grs[o]=rsqrtf(var+EPSF);
  }
  __syncthreads();
  int g = o>>4;
  psl[o] = (s1[o]*(1.f/4096.f) - gmu[g])*grs[g]*gn_gamma[o] + gn_beta[o];
  __syncthreads();
  if (o<16){ float a = se_b1[o]; for(int c=0;c<128;c++) a += psl[c]*se_w1[o*128+c]; t1[o]=siluf_(a); }
  __syncthreads();
  float a = se_b2[o]; for(int j=0;j<16;j++) a += t1[j]*se_w2[o*16+j];
  float sev = sigmoidf_(a);
  sca[b*128+o] = grs[g]*gn_gamma[o]*sev;
  shb[b*128+o] = (gn_beta[o] - gmu[g]*grs[g]*gn_gamma[o])*sev;
}

// ---------------- final ----------------
__global__ void k_final(const bf16_t* __restrict__ outp, const float* __restrict__ x,
                        const float* __restrict__ sca, const float* __restrict__ shb,
                        const float* __restrict__ bias, const float* __restrict__ iscale,
                        float* __restrict__ out){
  float ts = tanhf(iscale[0]);
  size_t i = ((size_t)blockIdx.x*256 + threadIdx.x)*8;
  int bo = (int)(i>>12); int o = bo&127;
  float A = sca[bo], Bv = shb[bo] + bias[o];
  bf16x8 ov = *(const bf16x8*)(outp + i);
  float4 x0 = *(const float4*)(x+i), x1 = *(const float4*)(x+i+4);
  float4 r0, r1;
  r0.x = (float)ov[0]*A + Bv + ts*x0.x;
  r0.y = (float)ov[1]*A + Bv + ts*x0.y;
  r0.z = (float)ov[2]*A + Bv + ts*x0.z;
  r0.w = (float)ov[3]*A + Bv + ts*x0.w;
  r1.x = (float)ov[4]*A + Bv + ts*x1.x;
  r1.y = (float)ov[5]*A + Bv + ts*x1.y;
  r1.z = (float)ov[6]*A + Bv + ts*x1.z;
  r1.w = (float)ov[7]*A + Bv + ts*x1.w;
  *(float4*)(out+i) = r0; *(float4*)(out+i+4) = r1;
}

extern "C" void kernel_launch(void* const* d_in, const int* in_sizes, int n_in,
                              void* d_out, int out_size, void* d_ws, size_t ws_size,
                              hipStream_t stream){
  const float* x      = (const float*)d_in[0];
  const float* base_w = (const float*)d_in[1];
  const float* delta_w= (const float*)d_in[2];
  const float* kscale = (const float*)d_in[3];
  const float* gc_w1  = (const float*)d_in[4];
  const float* gc_w2  = (const float*)d_in[5];
  const float* rc_w   = (const float*)d_in[6];
  const float* bn_g   = (const float*)d_in[7];
  const float* bn_b   = (const float*)d_in[8];
  const float* bn_m   = (const float*)d_in[9];
  const float* bn_v   = (const float*)d_in[10];
  const float* rg_w   = (const float*)d_in[11];
  const float* gate_w = (const float*)d_in[12];
  const float* gate_b = (const float*)d_in[13];
  const float* cg_w1  = (const float*)d_in[14];
  const float* cg_b1  = (const float*)d_in[15];
  const float* cg_w2  = (const float*)d_in[16];
  const float* cg_b2  = (const float*)d_in[17];
  const float* sg_w   = (const float*)d_in[18];
  const float* gn_g   = (const float*)d_in[19];
  const float* gn_b   = (const float*)d_in[20];
  const float* se_w1  = (const float*)d_in[21];
  const float* se_b1  = (const float*)d_in[22];
  const float* se_w2  = (const float*)d_in[23];
  const float* se_b2  = (const float*)d_in[24];
  const float* iscale = (const float*)d_in[25];
  const float* bias   = (const float*)d_in[26];
  float* out = (float*)d_out;

  char* ws = (char*)d_ws;
  size_t off = 0;
  auto alloc = [&](size_t bytes)->void*{ void* p = ws + off; off += (bytes + 255) & ~(size_t)255; return p; };
  bf16_t* X2Q = (bf16_t*)alloc(16ull*4*4*68*68*8*2); // quad-split padded channels-last
  bf16_t* WCQ = (bf16_t*)alloc(589824ull*2);
  bf16_t* RCWQ= (bf16_t*)alloc(36864ull*2);
  bf16_t* LF  = (bf16_t*)alloc(16ull*4096*32*2);
  bf16_t* OUTP= (bf16_t*)alloc(16ull*128*4096*2);
  float* PC2  = (float*)alloc(2048*4);               // PC2+CSUM+CSSQ contiguous
  float* CSUM = (float*)alloc(2048*4);
  float* CSSQ = (float*)alloc(2048*4);
  float* P    = (float*)alloc(2048*4);
  float* GB   = (float*)alloc(2048*4);
  float* GATE = (float*)alloc(2048*4);
  float* GF   = (float*)alloc(512*4);
  float* SIN  = (float*)alloc(16ull*8192*4);
  float* SCA  = (float*)alloc(2048*4);
  float* SHB  = (float*)alloc(2048*4);

  (void)hipMemsetAsync(PC2, 0, 3*8192, stream);  // PC2, CSUM, CSSQ

  k_wprep  <<<2448, 256, 0, stream>>>(base_w, delta_w, kscale, rc_w, WCQ, RCWQ);
  k_pool   <<<2048, 256, 0, stream>>>(x, P);
  k_small1 <<<16,   128, 0, stream>>>(P, gc_w1, gc_w2, cg_w1, cg_b1, cg_w2, cg_b2, GB, GATE);
  k_spatial<<<1024, 256, 0, stream>>>(x, GB, SIN);
  k_zb     <<<256,  256, 0, stream>>>(X2Q);
  k_x2     <<<1024, 256, 0, stream>>>(x, GATE, SIN, sg_w, X2Q, PC2);
  k_small2 <<<16,    64, 0, stream>>>(PC2, rg_w, GF);
  k_router <<<512,  256, 0, stream>>>(X2Q, RCWQ, bn_g, bn_b, bn_m, bn_v, GF, LF);
  k_main   <<<1024, 256, 0, stream>>>(X2Q, WCQ, LF, gate_w, gate_b, OUTP, CSUM, CSSQ);
  k_small3 <<<16,   128, 0, stream>>>(CSUM, CSSQ, gn_g, gn_b, se_w1, se_b1, se_w2, se_b2, SCA, SHB);
  k_final  <<<4096, 256, 0, stream>>>(OUTP, x, SCA, SHB, bias, iscale, out);
}

// Round 7
// 258.517 us; speedup vs baseline: 9.3948x; 1.2426x over previous
//
#include <hip/hip_runtime.h>
#include <hip/hip_bf16.h>
#include <math.h>

typedef __bf16 bf16_t;
typedef __bf16 bf16x8 __attribute__((ext_vector_type(8)));
typedef __bf16 bf16x4 __attribute__((ext_vector_type(4)));
typedef float  f32x4  __attribute__((ext_vector_type(4)));

#define EPSF 1e-5f
#define TAUF 1.5f

__device__ __forceinline__ float sigmoidf_(float x){ return 1.f/(1.f+__expf(-x)); }
__device__ __forceinline__ float siluf_(float x){ return x*sigmoidf_(x); }

__device__ __forceinline__ void gload_lds16(const void* g, void* l){
  __builtin_amdgcn_global_load_lds((const __attribute__((address_space(1))) unsigned int*)g,
                                   (__attribute__((address_space(3))) unsigned int*)l, 16, 0, 0);
}

// ---------------- p[b,c] = mean_hw(x) ----------------
__global__ void k_pool(const float* __restrict__ x, float* __restrict__ p){
  int bc = blockIdx.x; const float* xr = x + (size_t)bc*4096;
  float s = 0.f;
  for (int i = threadIdx.x; i < 4096; i += 256) s += xr[i];
  __shared__ float sb[4];
  for (int off=32; off; off>>=1) s += __shfl_down(s, off);
  if ((threadIdx.x & 63)==0) sb[threadIdx.x>>6] = s;
  __syncthreads();
  if (threadIdx.x==0) p[bc] = (sb[0]+sb[1]+sb[2]+sb[3]) * (1.f/4096.f);
}

// ---------------- per-b tiny MLPs ----------------
__global__ void k_small1(const float* __restrict__ p, const float* __restrict__ gc_w1,
                         const float* __restrict__ gc_w2, const float* __restrict__ cg_w1,
                         const float* __restrict__ cg_b1, const float* __restrict__ cg_w2,
                         const float* __restrict__ cg_b2,
                         float* __restrict__ gbuf, float* __restrict__ gate){
  int b = blockIdx.x; int t = threadIdx.x; // 128 threads
  __shared__ float ps[128], h1[32], pc[128], c1[16];
  ps[t] = p[b*128+t];
  __syncthreads();
  if (t < 32){ float a=0.f; for(int c=0;c<128;c++) a += ps[c]*gc_w1[t*128+c]; h1[t]=siluf_(a); }
  __syncthreads();
  float a=0.f; for(int j=0;j<32;j++) a += h1[j]*gc_w2[t*32+j];
  float g = sigmoidf_(a);
  gbuf[b*128+t] = g; pc[t] = ps[t]*g;   // mean(x*g) = g*mean(x)
  __syncthreads();
  if (t < 16){ float a2=cg_b1[t]; for(int c=0;c<128;c++) a2 += pc[c]*cg_w1[t*128+c]; c1[t]=siluf_(a2); }
  __syncthreads();
  float a3=cg_b2[t]; for(int j=0;j<16;j++) a3 += c1[j]*cg_w2[t*16+j];
  gate[b*128+t] = g * sigmoidf_(a3);
}

// ---------------- s_in: mean/max over channels of x*g (1 row / block) ----------------
__global__ void k_spatial(const float* __restrict__ x, const float* __restrict__ gbuf,
                          float* __restrict__ sin_){
  int bi = blockIdx.x; int b = bi>>6; int h = bi&63;
  int wv = threadIdx.x>>6, w = threadIdx.x&63;
  __shared__ float psum[4][64], pmax[4][64];
  float sm=0.f, mx=-1e30f;
  const float* xb = x + (((size_t)b*128 + wv*32)*64 + h)*64 + w;
  const float* gb = gbuf + b*128 + wv*32;
  #pragma unroll 4
  for (int c=0;c<32;c++){
    float v = xb[(size_t)c*4096] * gb[c];
    sm += v; mx = fmaxf(mx, v);
  }
  psum[wv][w]=sm; pmax[wv][w]=mx;
  __syncthreads();
  if (threadIdx.x < 64){
    float s = psum[0][w]+psum[1][w]+psum[2][w]+psum[3][w];
    float m = fmaxf(fmaxf(pmax[0][w],pmax[1][w]),fmaxf(pmax[2][w],pmax[3][w]));
    sin_[b*8192 + h*64 + w]        = s*(1.f/128.f);
    sin_[b*8192 + 4096 + h*64 + w] = m;
  }
}

// ---------------- x2: fused 7x7 spatial-gate + gating + quad-split store ----------------
// X2Q layout: [b][h2(4)][q(4)][68][68][8ch], original (h,w) at padded (h+2, w+2)
__global__ void __launch_bounds__(256) k_x2(
    const float* __restrict__ x, const float* __restrict__ gate,
    const float* __restrict__ sin_, const float* __restrict__ sg_w,
    bf16_t* __restrict__ x2q, float* __restrict__ pc2){
  int bi = blockIdx.x; int b = bi>>6; int h = bi&63;
  __shared__ float tile[128*65];   // 33280 B, stride-65 (conflict-free)
  __shared__ float sh_sin[980];    // [c2(2)][r(7)][col(70)]
  __shared__ float sh_sgw[98];
  __shared__ float satt_row[64];
  int tid = threadIdx.x, wv = tid>>6, lane = tid&63;
  for (int i=tid;i<980;i+=256){
    int c2 = i/490; int rr = i - c2*490; int r = rr/70; int k = rr - r*70;
    int hh = h + r - 3; int ww = k - 3;
    float v = 0.f;
    if (hh>=0 && hh<64 && ww>=0 && ww<64) v = sin_[b*8192 + c2*4096 + hh*64 + ww];
    sh_sin[i] = v;
  }
  if (tid < 98) sh_sgw[tid] = sg_w[tid];
  __syncthreads();
  if (tid < 64){
    float a = 0.f;
    #pragma unroll
    for (int c2=0;c2<2;c2++)
      #pragma unroll
      for (int r=0;r<7;r++)
        #pragma unroll
        for (int j=0;j<7;j++)
          a += sh_sin[c2*490 + r*70 + tid + j] * sh_sgw[c2*49 + r*7 + j];
    satt_row[tid] = sigmoidf_(a);
  }
  __syncthreads();
  float sa = satt_row[lane];
  // phase A: 32 independent coalesced loads -> f32 tile (no cross-lane ops)
  const float* xb = x + (((size_t)b*128 + wv*32)*64 + h)*64 + lane;
  const float* gb = gate + b*128 + wv*32;
  #pragma unroll 8
  for (int i=0;i<32;i++)
    tile[(wv*32+i)*65 + lane] = xb[(size_t)i*4096] * gb[i] * sa;
  __syncthreads();
  // phase B: quad-split bf16 store
  for (int it=0; it<4; it++){
    int idx = it*256 + tid;
    int cq = idx>>6; int w = idx&63;
    int c0 = cq*8;
    bf16x8 v;
    #pragma unroll
    for (int e=0;e<8;e++) v[e] = (bf16_t)tile[(c0+e)*65 + w];
    *(bf16x8*)(x2q + (((((size_t)b*4 + (cq>>2))*4 + (cq&3))*68 + (h+2))*68 + (w+2))*8) = v;
  }
  // phase C: per-channel row sum, one atomic per (b,c)
  if (tid < 128){
    const float* row = &tile[tid*65];
    float s = 0.f;
    #pragma unroll 8
    for (int w=0;w<64;w++) s += row[w];
    atomicAdd(&pc2[b*128+tid], s);
  }
}

// ---------------- weight prep (+ X2Q border zeroing fused) ----------------
// WCQ [ob(8)][t(9)][h2(4)][s(4)][q(4)][o16(16)][c8(8)] bf16, W'_s = base + delta_s*scale
// RCWQ [h2(4)][t(9)][n2(2)][q(4)][h16(16)][c8(8)] bf16
__global__ void k_wprep(const float* __restrict__ base_w, const float* __restrict__ delta_w,
                        const float* __restrict__ kscale, const float* __restrict__ rc_w,
                        bf16_t* __restrict__ WCQ, bf16_t* __restrict__ RCWQ,
                        bf16_t* __restrict__ x2q){
  int bx = blockIdx.x;
  if (bx >= 2448){
    // zero X2Q borders: 256 planes of [68][68][8]
    int p = bx - 2448;
    size_t base = (size_t)p*68*68*8;
    float4 z = {0.f,0.f,0.f,0.f};
    for (int i = threadIdx.x; i < 272; i += 256){
      int r = i/68; int wp = i - r*68;
      int hp = (r&1) + (r>>1)*66;
      *(float4*)(x2q + base + ((size_t)hp*68 + wp)*8) = z;
    }
    {
      int i = threadIdx.x;
      int hp = 2 + (i>>2);
      int wp = (i&1) + (i&2)*33;
      *(float4*)(x2q + base + ((size_t)hp*68 + wp)*8) = z;
    }
    return;
  }
  int i = bx*256 + threadIdx.x;
  if (i < 589824){
    int c8 = i&7; int o16 = (i>>3)&15; int q = (i>>7)&3; int s = (i>>9)&3;
    int h2 = (i>>11)&3; int r = i>>13; int t = r%9; int ob = r/9;
    int o = ob*16 + o16; int c = h2*32 + q*8 + c8;
    float v = base_w[(o*128+c)*9 + t] + delta_w[(((s*128)+o)*128 + c)*9 + t]*kscale[s*128+o];
    WCQ[i] = (bf16_t)v;
  } else if (i < 589824 + 36864){
    int j = i - 589824;
    int c8 = j&7; int h16 = (j>>3)&15; int q = (j>>7)&3; int n2 = (j>>9)&1;
    int r = j>>10; int t = r%9; int h2 = r/9;
    int hid = n2*16 + h16; int c = h2*32 + q*8 + c8;
    RCWQ[j] = (bf16_t)rc_w[(hid*128+c)*9 + t];
  }
}

// ---------------- router: strip + all-taps-resident MFMA, gf fused ----------------
// grid 512 = b(16) x rb(32 strips of 2 rows). M=128 pos, N=32 hid, K=1152.
__global__ void __launch_bounds__(256) k_router(
    const bf16_t* __restrict__ x2q, const bf16_t* __restrict__ RCWQ,
    const float* __restrict__ bn_gamma, const float* __restrict__ bn_beta,
    const float* __restrict__ bn_mean, const float* __restrict__ bn_var,
    const float* __restrict__ pc2, const float* __restrict__ rg_w,
    bf16_t* __restrict__ lfb){
  __shared__ __align__(16) char smem[44544]; // strip 4x6528=26112 + weights 18432
  __shared__ float sgf[32];
  __shared__ float spart[256];
  int tid = threadIdx.x;
  int wv = tid>>6, lane = tid&63, m16 = lane&15, q = lane>>4;
  int rb = blockIdx.x & 31, b = blockIdx.x >> 5;
  int r0 = rb*2;
  int rloc = wv&1;
  int ws0 = (wv>>1)*2;

  // fused gf = silu(mean(x2) @ rg_w^T): 256 threads = hid(32) x seg(8 of 16ch)
  {
    int hid = tid&31, seg = tid>>5;
    float a=0.f;
    #pragma unroll
    for (int j=0;j<16;j++) a += pc2[b*128 + seg*16 + j]*rg_w[hid*128 + seg*16 + j];
    spart[tid] = a;
  }

  f32x4 acc[2][2] = {};   // [n2][mt]

  #pragma unroll 1
  for (int h2=0; h2<4; h2++){
    const char* asrc = (const char*)(x2q + ((((size_t)(b*4+h2)*4 + wv)*68 + r0)*68)*8);
    #pragma unroll
    for (int j=0;j<7;j++){
      if (j*64 + lane < 408)
        gload_lds16(asrc + j*1024 + lane*16, (char*)smem + wv*6528 + j*1024);
    }
    const char* wsrc = (const char*)(RCWQ + (size_t)h2*9216) + wv*4608;
    #pragma unroll
    for (int j=0;j<5;j++){
      if (j*64 + lane < 288)
        gload_lds16(wsrc + j*1024 + lane*16, (char*)smem + 26112 + wv*4608 + j*1024);
    }
    __syncthreads();
    if (h2==0 && tid < 32){
      float s = 0.f;
      #pragma unroll
      for (int k=0;k<8;k++) s += spart[k*32+tid];
      sgf[tid] = siluf_(s*(1.f/4096.f));
    }
    #pragma unroll
    for (int t=0; t<9; t++){
      int di = t/3, dj = t - di*3;
      bf16x8 aw0 = *(const bf16x8*)((const char*)smem + 26112 + (t*2+0)*1024 + q*256 + m16*16);
      bf16x8 aw1 = *(const bf16x8*)((const char*)smem + 26112 + (t*2+1)*1024 + q*256 + m16*16);
      #pragma unroll
      for (int mt=0; mt<2; mt++){
        int wseg = ws0 + mt;
        bf16x8 bs = *(const bf16x8*)((const char*)smem + q*6528 +
                     ((rloc + 2*di)*68 + wseg*16 + m16 + 2*dj)*16);
        acc[0][mt] = __builtin_amdgcn_mfma_f32_16x16x32_bf16(aw0, bs, acc[0][mt], 0,0,0);
        acc[1][mt] = __builtin_amdgcn_mfma_f32_16x16x32_bf16(aw1, bs, acc[1][mt], 0,0,0);
      }
    }
    __syncthreads();
  }

  #pragma unroll
  for (int n2=0;n2<2;n2++){
    float aa[4], bb[4];
    #pragma unroll
    for (int i=0;i<4;i++){
      int hid = n2*16 + q*4 + i;
      float a = bn_gamma[hid]*rsqrtf(bn_var[hid]+EPSF);
      aa[i] = a;
      bb[i] = bn_beta[hid] - bn_mean[hid]*a;
    }
    #pragma unroll
    for (int mt=0;mt<2;mt++){
      bf16x4 yv;
      #pragma unroll
      for (int i=0;i<4;i++){
        int hid = n2*16 + q*4 + i;
        yv[i] = (bf16_t)(siluf_(aa[i]*acc[n2][mt][i] + bb[i]) + sgf[hid]);
      }
      size_t pos = (size_t)b*4096 + (r0+rloc)*64 + (ws0+mt)*16 + m16;
      *(bf16x4*)(lfb + pos*32 + n2*16 + q*4) = yv;
    }
  }
}

// ---------------- main dynamic conv: all-taps-resident implicit GEMM ----------------
// grid: 1024 = ob(8) x b(16) x hb(8)
// M=512 (8 rows x 64 w), N=64 (4 segs x 16 o), K=1152. 8 barriers total.
__global__ void __launch_bounds__(256, 2) k_main(
    const bf16_t* __restrict__ x2q, const bf16_t* __restrict__ WCQ,
    const bf16_t* __restrict__ lfb, const float* __restrict__ gate_w,
    const float* __restrict__ gate_b, bf16_t* __restrict__ outp,
    float* __restrict__ csum, float* __restrict__ cssq){
  __shared__ __align__(16) char smem[80960];
  bf16_t* shGW  = (bf16_t*)(smem + 43584);
  float*  sred  = (float*)(smem + 80448);

  int tid = threadIdx.x;
  int wv = tid>>6, lane = tid&63, m16 = lane&15, q = lane>>4;
  int bx = blockIdx.x;
  int ob = bx >> 7; int rem = bx & 127; int b = rem >> 3; int hb = rem & 7;
  int h0 = hb*8, obase = ob*16;

  f32x4 acc[8][4] = {};

  int baseA[8];
  #pragma unroll
  for (int mi=0;mi<8;mi++){
    int row = wv*2 + (mi>>2); int wseg = mi&3;
    baseA[mi] = (row*68 + wseg*16 + m16 + 1)*16 + q*10896;
  }
  int baseB = q*256 + m16*16;

  #pragma unroll 1
  for (int h2=0; h2<4; h2++){
    const char* asrc = (const char*)(x2q + ((((size_t)(b*4+h2)*4 + wv)*68 + (h0+1))*68)*8);
    #pragma unroll
    for (int j=0;j<11;j++){
      if (j*64 + lane < 680)
        gload_lds16(asrc + j*1024 + lane*16, (char*)smem + wv*10896 + j*1024);
    }
    const char* bsrc = (const char*)WCQ + ((size_t)(ob*9)*4 + h2)*4096;
    #pragma unroll
    for (int j=0;j<9;j++)
      gload_lds16(bsrc + j*16384 + wv*1024 + lane*16,
                  (char*)smem + 43584 + j*4096 + wv*1024);
    __syncthreads();
    #pragma unroll
    for (int t=0; t<9; t++){
      int di = t/3, dj = t - di*3;
      int toff = (di*68 + dj)*16;
      bf16x8 av[8], bv[4];
      #pragma unroll
      for (int mi=0;mi<8;mi++) av[mi] = *(const bf16x8*)((const char*)smem + baseA[mi] + toff);
      #pragma unroll
      for (int s=0;s<4;s++)  bv[s] = *(const bf16x8*)((const char*)smem + 43584 + t*4096 + s*1024 + baseB);
      #pragma unroll
      for (int s=0;s<4;s++){
        #pragma unroll
        for (int mi=0;mi<8;mi++)
          acc[mi][s] = __builtin_amdgcn_mfma_f32_16x16x32_bf16(av[mi], bv[s], acc[mi][s], 0,0,0);
      }
    }
    __syncthreads();
  }

  // ---- epilogue: gate logits + softmax + combine + GN-stats ----
  const char* lfsrc = (const char*)(lfb + ((size_t)b*4096 + h0*64)*32);
  for (int i = wv; i < 32; i += 4)
    gload_lds16(lfsrc + i*1024 + lane*16, (char*)smem + i*1024);
  for (int idx = tid; idx < 2048; idx += 256){
    int n = idx>>5, j = idx&31;
    shGW[n*32+j] = (bf16_t)gate_w[((n>>4)*128 + obase + (n&15))*32 + j];
  }
  __syncthreads();

  bf16x8 bg[4];
  #pragma unroll
  for (int kk=0;kk<4;kk++) bg[kk] = *(const bf16x8*)((const char*)shGW + (kk*16+m16)*64 + q*16);
  float gb[4];
  #pragma unroll
  for (int kk=0;kk<4;kk++) gb[kk] = gate_b[kk*128 + obase + m16];

  const float itau = 1.f/TAUF;
  float s1 = 0.f, s2 = 0.f;
  size_t orow = ((size_t)(b*128 + obase + m16))*4096 + h0*64;
  #pragma unroll
  for (int mi=0; mi<8; mi++){
    bf16x8 avL = *(const bf16x8*)((const char*)smem + (wv*128 + mi*16 + m16)*64 + q*16);
    f32x4 zero = {};
    f32x4 lg[4];
    #pragma unroll
    for (int kk=0;kk<4;kk++)
      lg[kk] = __builtin_amdgcn_mfma_f32_16x16x32_bf16(avL, bg[kk], zero, 0,0,0);
    bf16x4 yv;
    #pragma unroll
    for (int r=0;r<4;r++){
      float l0 = (lg[0][r]+gb[0])*itau, l1 = (lg[1][r]+gb[1])*itau;
      float l2 = (lg[2][r]+gb[2])*itau, l3 = (lg[3][r]+gb[3])*itau;
      float mx = fmaxf(fmaxf(l0,l1),fmaxf(l2,l3));
      float e0=__expf(l0-mx), e1=__expf(l1-mx), e2=__expf(l2-mx), e3=__expf(l3-mx);
      float inv = 1.f/(e0+e1+e2+e3);
      float y = (e0*acc[mi][0][r] + e1*acc[mi][1][r]
               + e2*acc[mi][2][r] + e3*acc[mi][3][r])*inv;
      s1 += y; s2 += y*y;
      yv[r] = (bf16_t)y;
    }
    *(bf16x4*)(outp + orow + wv*128 + mi*16 + q*4) = yv;
  }

  s1 += __shfl_down(s1, 32); s1 += __shfl_down(s1, 16);
  s2 += __shfl_down(s2, 32); s2 += __shfl_down(s2, 16);
  if (lane < 16){ sred[wv*16 + lane] = s1; sred[64 + wv*16 + lane] = s2; }
  __syncthreads();
  if (tid < 16){
    float a = sred[tid] + sred[16+tid] + sred[32+tid] + sred[48+tid];
    float c = sred[64+tid] + sred[80+tid] + sred[96+tid] + sred[112+tid];
    atomicAdd(&csum[b*128 + obase + tid], a);
    atomicAdd(&cssq[b*128 + obase + tid], c);
  }
}

// ---------------- GroupNorm stats + output-SE -> per-(b,o) affine ----------------
__global__ void k_small3(const float* __restrict__ csum, const float* __restrict__ cssq,
                         const float* __restrict__ gn_gamma, const float* __restrict__ gn_beta,
                         const float* __restrict__ se_w1, const float* __restrict__ se_b1,
                         const float* __restrict__ se_w2, const float* __restrict__ se_b2,
                         float* __restrict__ sca, float* __restrict__ shb){
  int b = blockIdx.x; int o = threadIdx.x; // 128
  __shared__ float s1[128], s2[128], gmu[8], grs[8], psl[128], t1[16];
  s1[o] = csum[b*128+o]; s2[o] = cssq[b*128+o];
  __syncthreads();
  if (o<8){
    float a=0.f,a2=0.f; for(int j=0;j<16;j++){ a+=s1[o*16+j]; a2+=s2[o*16+j]; }
    float mu = a*(1.f/65536.f); float var = a2*(1.f/65536.f) - mu*mu;
    gmu[o]=mu; grs[o]=rsqrtf(var+EPSF);
  }
  __syncthreads();
  int g = o>>4;
  psl[o] = (s1[o]*(1.f/4096.f) - gmu[g])*grs[g]*gn_gamma[o] + gn_beta[o];
  __syncthreads();
  if (o<16){ float a = se_b1[o]; for(int c=0;c<128;c++) a += psl[c]*se_w1[o*128+c]; t1[o]=siluf_(a); }
  __syncthreads();
  float a = se_b2[o]; for(int j=0;j<16;j++) a += t1[j]*se_w2[o*16+j];
  float sev = sigmoidf_(a);
  sca[b*128+o] = grs[g]*gn_gamma[o]*sev;
  shb[b*128+o] = (gn_beta[o] - gmu[g]*grs[g]*gn_gamma[o])*sev;
}

// ---------------- final ----------------
__global__ void k_final(const bf16_t* __restrict__ outp, const float* __restrict__ x,
                        const float* __restrict__ sca, const float* __restrict__ shb,
                        const float* __restrict__ bias, const float* __restrict__ iscale,
                        float* __restrict__ out){
  float ts = tanhf(iscale[0]);
  size_t i = ((size_t)blockIdx.x*256 + threadIdx.x)*8;
  int bo = (int)(i>>12); int o = bo&127;
  float A = sca[bo], Bv = shb[bo] + bias[o];
  bf16x8 ov = *(const bf16x8*)(outp + i);
  float4 x0 = *(const float4*)(x+i), x1 = *(const float4*)(x+i+4);
  float4 r0, r1;
  r0.x = (float)ov[0]*A + Bv + ts*x0.x;
  r0.y = (float)ov[1]*A + Bv + ts*x0.y;
  r0.z = (float)ov[2]*A + Bv + ts*x0.z;
  r0.w = (float)ov[3]*A + Bv + ts*x0.w;
  r1.x = (float)ov[4]*A + Bv + ts*x1.x;
  r1.y = (float)ov[5]*A + Bv + ts*x1.y;
  r1.z = (float)ov[6]*A + Bv + ts*x1.z;
  r1.w = (float)ov[7]*A + Bv + ts*x1.w;
  *(float4*)(out+i) = r0; *(float4*)(out+i+4) = r1;
}

extern "C" void kernel_launch(void* const* d_in, const int* in_sizes, int n_in,
                              void* d_out, int out_size, void* d_ws, size_t ws_size,
                              hipStream_t stream){
  const float* x      = (const float*)d_in[0];
  const float* base_w = (const float*)d_in[1];
  const float* delta_w= (const float*)d_in[2];
  const float* kscale = (const float*)d_in[3];
  const float* gc_w1  = (const float*)d_in[4];
  const float* gc_w2  = (const float*)d_in[5];
  const float* rc_w   = (const float*)d_in[6];
  const float* bn_g   = (const float*)d_in[7];
  const float* bn_b   = (const float*)d_in[8];
  const float* bn_m   = (const float*)d_in[9];
  const float* bn_v   = (const float*)d_in[10];
  const float* rg_w   = (const float*)d_in[11];
  const float* gate_w = (const float*)d_in[12];
  const float* gate_b = (const float*)d_in[13];
  const float* cg_w1  = (const float*)d_in[14];
  const float* cg_b1  = (const float*)d_in[15];
  const float* cg_w2  = (const float*)d_in[16];
  const float* cg_b2  = (const float*)d_in[17];
  const float* sg_w   = (const float*)d_in[18];
  const float* gn_g   = (const float*)d_in[19];
  const float* gn_b   = (const float*)d_in[20];
  const float* se_w1  = (const float*)d_in[21];
  const float* se_b1  = (const float*)d_in[22];
  const float* se_w2  = (const float*)d_in[23];
  const float* se_b2  = (const float*)d_in[24];
  const float* iscale = (const float*)d_in[25];
  const float* bias   = (const float*)d_in[26];
  float* out = (float*)d_out;

  char* ws = (char*)d_ws;
  size_t off = 0;
  auto alloc = [&](size_t bytes)->void*{ void* p = ws + off; off += (bytes + 255) & ~(size_t)255; return p; };
  bf16_t* X2Q = (bf16_t*)alloc(16ull*4*4*68*68*8*2); // quad-split padded channels-last
  bf16_t* WCQ = (bf16_t*)alloc(589824ull*2);
  bf16_t* RCWQ= (bf16_t*)alloc(36864ull*2);
  bf16_t* LF  = (bf16_t*)alloc(16ull*4096*32*2);
  bf16_t* OUTP= (bf16_t*)alloc(16ull*128*4096*2);
  float* PC2  = (float*)alloc(2048*4);               // PC2+CSUM+CSSQ contiguous
  float* CSUM = (float*)alloc(2048*4);
  float* CSSQ = (float*)alloc(2048*4);
  float* P    = (float*)alloc(2048*4);
  float* GB   = (float*)alloc(2048*4);
  float* GATE = (float*)alloc(2048*4);
  float* SIN  = (float*)alloc(16ull*8192*4);
  float* SCA  = (float*)alloc(2048*4);
  float* SHB  = (float*)alloc(2048*4);

  (void)hipMemsetAsync(PC2, 0, 3*8192, stream);  // PC2, CSUM, CSSQ

  k_wprep  <<<2704, 256, 0, stream>>>(base_w, delta_w, kscale, rc_w, WCQ, RCWQ, X2Q);
  k_pool   <<<2048, 256, 0, stream>>>(x, P);
  k_small1 <<<16,   128, 0, stream>>>(P, gc_w1, gc_w2, cg_w1, cg_b1, cg_w2, cg_b2, GB, GATE);
  k_spatial<<<1024, 256, 0, stream>>>(x, GB, SIN);
  k_x2     <<<1024, 256, 0, stream>>>(x, GATE, SIN, sg_w, X2Q, PC2);
  k_router <<<512,  256, 0, stream>>>(X2Q, RCWQ, bn_g, bn_b, bn_m, bn_v, PC2, rg_w, LF);
  k_main   <<<1024, 256, 0, stream>>>(X2Q, WCQ, LF, gate_w, gate_b, OUTP, CSUM, CSSQ);
  k_small3 <<<16,   128, 0, stream>>>(CSUM, CSSQ, gn_g, gn_b, se_w1, se_b1, se_w2, se_b2, SCA, SHB);
  k_final  <<<4096, 256, 0, stream>>>(OUTP, x, SCA, SHB, bias, iscale, out);
}